// Round 1
// baseline (506.126 us; speedup 1.0000x reference)
//
#include <hip/hip_runtime.h>
#include <cstdint>

#define B_    2
#define T_    2048
#define H_    1024
#define DIN_  2048
#define NS_   16
#define M_    (B_*T_)     // 4096
#define NCHUNK 32
#define LCHUNK 64         // T_/NCHUNK

using bf16x8 = __attribute__((ext_vector_type(8))) short;
using f32x4  = __attribute__((ext_vector_type(4))) float;

__device__ __forceinline__ unsigned short f2bf(float f) {
    union { float f; uint32_t u; } x; x.f = f;
    uint32_t u = x.u;
    uint32_t r = (u + 0x7fffu + ((u >> 16) & 1u)) >> 16;
    return (unsigned short)r;
}
__device__ __forceinline__ float bf2f(unsigned short h) {
    union { uint32_t u; float f; } x; x.u = ((uint32_t)h) << 16;
    return x.f;
}
__device__ __forceinline__ float sigm(float v) { return 1.0f / (1.0f + expf(-v)); }
__device__ __forceinline__ float silu(float v) { return v / (1.0f + expf(-v)); }

__device__ __forceinline__ void gload_lds16(const void* g, void* l) {
    __builtin_amdgcn_global_load_lds(
        (__attribute__((address_space(1))) void*)(void*)g,
        (__attribute__((address_space(3))) void*)l, 16, 0, 0);
}

// ---------------- transpose + bf16 hi/lo split: W[K][N] -> T{h,l}[N][K] ----------------
__global__ __launch_bounds__(256)
void transpose_split(const float* __restrict__ W, unsigned short* __restrict__ Th,
                     unsigned short* __restrict__ Tl, int K, int N) {
    __shared__ float tile[32][33];
    int n0 = blockIdx.x * 32, k0 = blockIdx.y * 32;
    int tx = threadIdx.x & 31, ty = threadIdx.x >> 5;   // ty 0..7
#pragma unroll
    for (int i = 0; i < 32; i += 8)
        tile[ty + i][tx] = W[(size_t)(k0 + ty + i) * N + (n0 + tx)];
    __syncthreads();
#pragma unroll
    for (int i = 0; i < 32; i += 8) {
        float v = tile[tx][ty + i];
        size_t o = (size_t)(n0 + ty + i) * K + (k0 + tx);
        unsigned short h = f2bf(v);
        Th[o] = h;
        Tl[o] = f2bf(v - bf2f(h));
    }
}

// ---------------- RMSNorm + bf16 hi/lo split ----------------
__global__ __launch_bounds__(256)
void rmsnorm_split(const float* __restrict__ x, const float* __restrict__ w,
                   unsigned short* __restrict__ xh, unsigned short* __restrict__ xl) {
    int row = blockIdx.x;            // 0..4095
    int tid = threadIdx.x;
    const float4* xr = (const float4*)(x + (size_t)row * H_);
    float4 v = xr[tid];
    float ss = v.x * v.x + v.y * v.y + v.z * v.z + v.w * v.w;
#pragma unroll
    for (int o = 32; o > 0; o >>= 1) ss += __shfl_down(ss, o, 64);
    __shared__ float red[4];
    int lane = tid & 63, wv = tid >> 6;
    if (lane == 0) red[wv] = ss;
    __syncthreads();
    float tot = red[0] + red[1] + red[2] + red[3];
    float rstd = rsqrtf(tot / (float)H_ + 1e-6f);
    const float4* wr = (const float4*)w;
    float4 w4 = wr[tid];
    float s0 = v.x * rstd * w4.x, s1 = v.y * rstd * w4.y;
    float s2 = v.z * rstd * w4.z, s3 = v.w * rstd * w4.w;
    size_t o = (size_t)row * H_ + tid * 4;
    unsigned short h0 = f2bf(s0), h1 = f2bf(s1), h2 = f2bf(s2), h3 = f2bf(s3);
    *(ushort4*)&xh[o] = make_ushort4(h0, h1, h2, h3);
    *(ushort4*)&xl[o] = make_ushort4(f2bf(s0 - bf2f(h0)), f2bf(s1 - bf2f(h1)),
                                     f2bf(s2 - bf2f(h2)), f2bf(s3 - bf2f(h3)));
}

// ---------------- bf16x3 split GEMM: C = (Ah+Al) @ (Bh+Bl)^T, 128x128 tile ----------------
// EPI 0: xz epilogue -> silu; col<2048: split to oh/ol (x_in), else out0 (silu_z)
// EPI 1: a_mod = sigmoid(acc + aux[col]) -> out0
// EPI 2: out0 = acc + aux[row*N+col]   (residual add)
template <int EPI>
__global__ __launch_bounds__(256)
void gemm_x3(const unsigned short* __restrict__ Ah, const unsigned short* __restrict__ Al,
             const unsigned short* __restrict__ Bh, const unsigned short* __restrict__ Bl,
             int M, int N, int K,
             float* __restrict__ out0,
             unsigned short* __restrict__ oh, unsigned short* __restrict__ ol,
             const float* __restrict__ aux) {
    __shared__ unsigned short sm[4][128 * 32];   // Ah,Al,Bh,Bl tiles: 8KB each
    const int tid  = threadIdx.x;
    const int lane = tid & 63;
    const int wid  = tid >> 6;
    const int wm   = wid >> 1, wn = wid & 1;
    const int bm   = blockIdx.y * 128;
    const int bn   = blockIdx.x * 128;

    const unsigned short* src;
    int srow;
    if (wid == 0)      { src = Ah; srow = bm; }
    else if (wid == 1) { src = Al; srow = bm; }
    else if (wid == 2) { src = Bh; srow = bn; }
    else               { src = Bl; srow = bn; }
    const int lrow = lane >> 2;          // 0..15 within 16-row group
    const int lcol = (lane & 3) * 8;     // bf16 element offset (16B granules)

    f32x4 acc[4][4] = {};

    const int nk = K >> 5;
    for (int kt = 0; kt < nk; ++kt) {
        // stage: each wave stages its matrix (128 rows x 64B), 8 x 1KB wave-issues
#pragma unroll
        for (int i = 0; i < 8; ++i) {
            const unsigned short* g =
                src + (size_t)(srow + i * 16 + lrow) * K + (size_t)(kt * 32 + lcol);
            gload_lds16(g, &sm[wid][i * 512]);
        }
        __syncthreads();   // drains vmcnt(0): LDS tiles ready

        const int kofs = (lane >> 4) * 8;
        const int lr   = lane & 15;
        bf16x8 af[2][4], bfr[2][4];
#pragma unroll
        for (int m = 0; m < 4; ++m) {
            af[0][m] = *(const bf16x8*)&sm[0][(wm * 64 + m * 16 + lr) * 32 + kofs];
            af[1][m] = *(const bf16x8*)&sm[1][(wm * 64 + m * 16 + lr) * 32 + kofs];
        }
#pragma unroll
        for (int n = 0; n < 4; ++n) {
            bfr[0][n] = *(const bf16x8*)&sm[2][(wn * 64 + n * 16 + lr) * 32 + kofs];
            bfr[1][n] = *(const bf16x8*)&sm[3][(wn * 64 + n * 16 + lr) * 32 + kofs];
        }
#pragma unroll
        for (int m = 0; m < 4; ++m)
#pragma unroll
            for (int n = 0; n < 4; ++n) {
                acc[m][n] = __builtin_amdgcn_mfma_f32_16x16x32_bf16(af[0][m], bfr[0][n], acc[m][n], 0, 0, 0);
                acc[m][n] = __builtin_amdgcn_mfma_f32_16x16x32_bf16(af[0][m], bfr[1][n], acc[m][n], 0, 0, 0);
                acc[m][n] = __builtin_amdgcn_mfma_f32_16x16x32_bf16(af[1][m], bfr[0][n], acc[m][n], 0, 0, 0);
            }
        __syncthreads();   // protect LDS before next stage
    }

    // epilogue: C/D layout col=lane&15, row=(lane>>4)*4+reg  [m89-verified]
#pragma unroll
    for (int m = 0; m < 4; ++m)
#pragma unroll
        for (int n = 0; n < 4; ++n) {
            int col  = bn + wn * 64 + n * 16 + (lane & 15);
            int row0 = bm + wm * 64 + m * 16 + ((lane >> 4) << 2);
#pragma unroll
            for (int r = 0; r < 4; ++r) {
                int row = row0 + r;
                float v = acc[m][n][r];
                if (EPI == 0) {
                    float s = silu(v);
                    if (col < DIN_) {
                        unsigned short h16 = f2bf(s);
                        oh[(size_t)row * DIN_ + col] = h16;
                        ol[(size_t)row * DIN_ + col] = f2bf(s - bf2f(h16));
                    } else {
                        out0[(size_t)row * DIN_ + (col - DIN_)] = s;
                    }
                } else if (EPI == 1) {
                    out0[(size_t)row * N + col] = sigm(v + aux[col]);
                } else {
                    out0[(size_t)row * N + col] = v + aux[(size_t)row * N + col];
                }
            }
        }
}

// ---------------- B_in / C_in projections (N=16 each), fp32 via hi+lo ----------------
__global__ __launch_bounds__(256)
void bc_proj(const unsigned short* __restrict__ xh, const unsigned short* __restrict__ xl,
             const float* __restrict__ Bw, const float* __restrict__ Cw,
             float* __restrict__ Bout, float* __restrict__ Cout) {
    int m = blockIdx.x;
    int tid = threadIdx.x;
    float ab[16], ac[16];
#pragma unroll
    for (int i = 0; i < 16; ++i) { ab[i] = 0.f; ac[i] = 0.f; }
    for (int k = tid; k < DIN_; k += 256) {
        size_t xi = (size_t)m * DIN_ + k;
        float x = bf2f(xh[xi]) + bf2f(xl[xi]);
        const float4* br = (const float4*)(Bw + (size_t)k * 16);
        const float4* cr = (const float4*)(Cw + (size_t)k * 16);
#pragma unroll
        for (int j = 0; j < 4; ++j) {
            float4 b4 = br[j], c4 = cr[j];
            ab[j * 4 + 0] = fmaf(x, b4.x, ab[j * 4 + 0]);
            ab[j * 4 + 1] = fmaf(x, b4.y, ab[j * 4 + 1]);
            ab[j * 4 + 2] = fmaf(x, b4.z, ab[j * 4 + 2]);
            ab[j * 4 + 3] = fmaf(x, b4.w, ab[j * 4 + 3]);
            ac[j * 4 + 0] = fmaf(x, c4.x, ac[j * 4 + 0]);
            ac[j * 4 + 1] = fmaf(x, c4.y, ac[j * 4 + 1]);
            ac[j * 4 + 2] = fmaf(x, c4.z, ac[j * 4 + 2]);
            ac[j * 4 + 3] = fmaf(x, c4.w, ac[j * 4 + 3]);
        }
    }
    int lane = tid & 63, w = tid >> 6;
#pragma unroll
    for (int i = 0; i < 16; ++i)
#pragma unroll
        for (int o = 32; o > 0; o >>= 1) {
            ab[i] += __shfl_down(ab[i], o, 64);
            ac[i] += __shfl_down(ac[i], o, 64);
        }
    __shared__ float rb[4][16], rc[4][16];
    if (lane == 0) {
#pragma unroll
        for (int i = 0; i < 16; ++i) { rb[w][i] = ab[i]; rc[w][i] = ac[i]; }
    }
    __syncthreads();
    if (tid < 16) {
        Bout[(size_t)m * 16 + tid] = rb[0][tid] + rb[1][tid] + rb[2][tid] + rb[3][tid];
        Cout[(size_t)m * 16 + tid] = rc[0][tid] + rc[1][tid] + rc[2][tid] + rc[3][tid];
    }
}

// ---------------- chunked parallel scan ----------------
// phase1: per chunk, P = prod(decay), S = state from zero init
__global__ __launch_bounds__(256)
void scan_phase1(const float* __restrict__ amod, const unsigned short* __restrict__ xh,
                 const unsigned short* __restrict__ xl, const float* __restrict__ Bin,
                 const float* __restrict__ Abase,
                 float* __restrict__ P, float* __restrict__ S) {
    int d = blockIdx.x * 256 + threadIdx.x;   // 0..2047
    int c = blockIdx.y;
    int b = blockIdx.z;
    float ab[16];
#pragma unroll
    for (int n = 0; n < 16; ++n) ab[n] = sigm(Abase[n]);
    float p[16], s[16];
#pragma unroll
    for (int n = 0; n < 16; ++n) { p[n] = 1.0f; s[n] = 0.0f; }
    int t0 = c * LCHUNK;
    for (int tt = 0; tt < LCHUNK; ++tt) {
        size_t mrow = (size_t)(b * T_ + t0 + tt);
        float a = amod[mrow * DIN_ + d];
        float x = bf2f(xh[mrow * DIN_ + d]) + bf2f(xl[mrow * DIN_ + d]);
        const float4* bt4 = (const float4*)(Bin + mrow * 16);
        float4 q0 = bt4[0], q1 = bt4[1], q2 = bt4[2], q3 = bt4[3];
        float bt[16];
        bt[0]=q0.x; bt[1]=q0.y; bt[2]=q0.z; bt[3]=q0.w;
        bt[4]=q1.x; bt[5]=q1.y; bt[6]=q1.z; bt[7]=q1.w;
        bt[8]=q2.x; bt[9]=q2.y; bt[10]=q2.z; bt[11]=q2.w;
        bt[12]=q3.x; bt[13]=q3.y; bt[14]=q3.z; bt[15]=q3.w;
#pragma unroll
        for (int n = 0; n < 16; ++n) {
            float dk = a * ab[n];
            p[n] *= dk;
            s[n] = fmaf(dk, s[n], bt[n] * x);
        }
    }
    size_t base = ((size_t)(b * NCHUNK + c) << 15) + (size_t)d * 16;
    float4* P4 = (float4*)(P + base);
    float4* S4 = (float4*)(S + base);
#pragma unroll
    for (int j = 0; j < 4; ++j) {
        P4[j] = make_float4(p[4*j], p[4*j+1], p[4*j+2], p[4*j+3]);
        S4[j] = make_float4(s[4*j], s[4*j+1], s[4*j+2], s[4*j+3]);
    }
}

// phase2: sequential prefix over chunks -> initial state per chunk
__global__ __launch_bounds__(256)
void scan_phase2(const float* __restrict__ P, const float* __restrict__ S,
                 float* __restrict__ H0) {
    int idx = blockIdx.x * 256 + threadIdx.x;   // 0..65535
    int b = idx >> 15;
    int dn = idx & 32767;
    float g = 0.f;
    for (int c = 0; c < NCHUNK; ++c) {
        size_t base = ((size_t)(b * NCHUNK + c) << 15) + dn;
        H0[base] = g;
        g = fmaf(P[base], g, S[base]);
    }
}

// phase3: replay with correct init, produce y_comb = (y + D*x)*silu_z, split to bf16
__global__ __launch_bounds__(256)
void scan_phase3(const float* __restrict__ amod, const unsigned short* __restrict__ xh,
                 const unsigned short* __restrict__ xl, const float* __restrict__ Bin,
                 const float* __restrict__ Cin, const float* __restrict__ Abase,
                 const float* __restrict__ H0, const float* __restrict__ Dp,
                 const float* __restrict__ sz,
                 unsigned short* __restrict__ yh, unsigned short* __restrict__ yl) {
    int d = blockIdx.x * 256 + threadIdx.x;
    int c = blockIdx.y;
    int b = blockIdx.z;
    float ab[16];
#pragma unroll
    for (int n = 0; n < 16; ++n) ab[n] = sigm(Abase[n]);
    float h[16];
    size_t hbase = ((size_t)(b * NCHUNK + c) << 15) + (size_t)d * 16;
    const float4* H4 = (const float4*)(H0 + hbase);
#pragma unroll
    for (int j = 0; j < 4; ++j) {
        float4 t4 = H4[j];
        h[j*4] = t4.x; h[j*4+1] = t4.y; h[j*4+2] = t4.z; h[j*4+3] = t4.w;
    }
    float Dd = Dp[d];
    int t0 = c * LCHUNK;
    for (int tt = 0; tt < LCHUNK; ++tt) {
        size_t mrow = (size_t)(b * T_ + t0 + tt);
        float a = amod[mrow * DIN_ + d];
        float x = bf2f(xh[mrow * DIN_ + d]) + bf2f(xl[mrow * DIN_ + d]);
        const float4* bt4 = (const float4*)(Bin + mrow * 16);
        const float4* ct4 = (const float4*)(Cin + mrow * 16);
        float4 q0 = bt4[0], q1 = bt4[1], q2 = bt4[2], q3 = bt4[3];
        float4 r0 = ct4[0], r1 = ct4[1], r2 = ct4[2], r3 = ct4[3];
        float bt[16], ct[16];
        bt[0]=q0.x; bt[1]=q0.y; bt[2]=q0.z; bt[3]=q0.w;
        bt[4]=q1.x; bt[5]=q1.y; bt[6]=q1.z; bt[7]=q1.w;
        bt[8]=q2.x; bt[9]=q2.y; bt[10]=q2.z; bt[11]=q2.w;
        bt[12]=q3.x; bt[13]=q3.y; bt[14]=q3.z; bt[15]=q3.w;
        ct[0]=r0.x; ct[1]=r0.y; ct[2]=r0.z; ct[3]=r0.w;
        ct[4]=r1.x; ct[5]=r1.y; ct[6]=r1.z; ct[7]=r1.w;
        ct[8]=r2.x; ct[9]=r2.y; ct[10]=r2.z; ct[11]=r2.w;
        ct[12]=r3.x; ct[13]=r3.y; ct[14]=r3.z; ct[15]=r3.w;
        float y = 0.f;
#pragma unroll
        for (int n = 0; n < 16; ++n) {
            float dk = a * ab[n];
            h[n] = fmaf(dk, h[n], bt[n] * x);
            y = fmaf(h[n], ct[n], y);
        }
        float val = (y + Dd * x) * sz[mrow * DIN_ + d];
        unsigned short vh = f2bf(val);
        yh[mrow * DIN_ + d] = vh;
        yl[mrow * DIN_ + d] = f2bf(val - bf2f(vh));
    }
}

// ---------------- launch ----------------
extern "C" void kernel_launch(void* const* d_in, const int* in_sizes, int n_in,
                              void* d_out, int out_size, void* d_ws, size_t ws_size,
                              hipStream_t stream) {
    const float* x          = (const float*)d_in[0];
    const float* norm_w     = (const float*)d_in[1];
    const float* in_proj_w  = (const float*)d_in[2];
    const float* A_proj_w   = (const float*)d_in[3];
    const float* A_proj_b   = (const float*)d_in[4];
    const float* A_base     = (const float*)d_in[5];
    const float* B_proj_w   = (const float*)d_in[6];
    const float* C_proj_w   = (const float*)d_in[7];
    const float* Dp         = (const float*)d_in[8];
    const float* out_proj_w = (const float*)d_in[9];
    float* out = (float*)d_out;

    char* ws = (char*)d_ws;
    size_t off = 0;
    auto alloc = [&](size_t bytes) -> char* {
        char* p = ws + off;
        off += (bytes + 255) & ~(size_t)255;
        return p;
    };
    unsigned short* inTh = (unsigned short*)alloc((size_t)4096 * 1024 * 2);
    unsigned short* inTl = (unsigned short*)alloc((size_t)4096 * 1024 * 2);
    unsigned short* ATh  = (unsigned short*)alloc((size_t)2048 * 2048 * 2);
    unsigned short* ATl  = (unsigned short*)alloc((size_t)2048 * 2048 * 2);
    unsigned short* OTh  = (unsigned short*)alloc((size_t)1024 * 2048 * 2);
    unsigned short* OTl  = (unsigned short*)alloc((size_t)1024 * 2048 * 2);
    unsigned short* xnh  = (unsigned short*)alloc((size_t)M_ * H_ * 2);
    unsigned short* xnl  = (unsigned short*)alloc((size_t)M_ * H_ * 2);
    unsigned short* xinh = (unsigned short*)alloc((size_t)M_ * DIN_ * 2);
    unsigned short* xinl = (unsigned short*)alloc((size_t)M_ * DIN_ * 2);
    float* silu_z = (float*)alloc((size_t)M_ * DIN_ * 4);
    float* amod   = (float*)alloc((size_t)M_ * DIN_ * 4);
    float* Bin    = (float*)alloc((size_t)M_ * 16 * 4);
    float* Cin    = (float*)alloc((size_t)M_ * 16 * 4);
    float* Pw     = (float*)alloc((size_t)B_ * NCHUNK * DIN_ * NS_ * 4);
    float* Sw     = (float*)alloc((size_t)B_ * NCHUNK * DIN_ * NS_ * 4);
    float* H0w    = (float*)alloc((size_t)B_ * NCHUNK * DIN_ * NS_ * 4);
    unsigned short* yh = (unsigned short*)alloc((size_t)M_ * DIN_ * 2);
    unsigned short* yl = (unsigned short*)alloc((size_t)M_ * DIN_ * 2);
    (void)ws_size;

    // weight prep: transpose + split
    transpose_split<<<dim3(4096 / 32, 1024 / 32), 256, 0, stream>>>(in_proj_w, inTh, inTl, 1024, 4096);
    transpose_split<<<dim3(2048 / 32, 2048 / 32), 256, 0, stream>>>(A_proj_w, ATh, ATl, 2048, 2048);
    transpose_split<<<dim3(1024 / 32, 2048 / 32), 256, 0, stream>>>(out_proj_w, OTh, OTl, 2048, 1024);

    rmsnorm_split<<<M_, 256, 0, stream>>>(x, norm_w, xnh, xnl);

    // xz = xn @ in_proj  (M=4096, N=4096, K=1024) -> x_in(split) + silu_z
    gemm_x3<0><<<dim3(4096 / 128, M_ / 128), 256, 0, stream>>>(
        xnh, xnl, inTh, inTl, M_, 4096, 1024, silu_z, xinh, xinl, nullptr);

    // a_mod = sigmoid(x_in @ A_proj + b)  (N=2048, K=2048)
    gemm_x3<1><<<dim3(2048 / 128, M_ / 128), 256, 0, stream>>>(
        xinh, xinl, ATh, ATl, M_, 2048, 2048, amod, nullptr, nullptr, A_proj_b);

    // B_in, C_in
    bc_proj<<<M_, 256, 0, stream>>>(xinh, xinl, B_proj_w, C_proj_w, Bin, Cin);

    // chunked scan
    scan_phase1<<<dim3(DIN_ / 256, NCHUNK, B_), 256, 0, stream>>>(amod, xinh, xinl, Bin, A_base, Pw, Sw);
    scan_phase2<<<(B_ * DIN_ * NS_) / 256, 256, 0, stream>>>(Pw, Sw, H0w);
    scan_phase3<<<dim3(DIN_ / 256, NCHUNK, B_), 256, 0, stream>>>(
        amod, xinh, xinl, Bin, Cin, A_base, H0w, Dp, silu_z, yh, yl);

    // out = residual + y @ out_proj  (N=1024, K=2048)
    gemm_x3<2><<<dim3(1024 / 128, M_ / 128), 256, 0, stream>>>(
        yh, yl, OTh, OTl, M_, 1024, 2048, out, nullptr, nullptr, x);
}

// Round 2
// 430.821 us; speedup vs baseline: 1.1748x; 1.1748x over previous
//
#include <hip/hip_runtime.h>
#include <cstdint>

#define B_    2
#define T_    2048
#define H_    1024
#define DIN_  2048
#define NS_   16
#define M_    (B_*T_)     // 4096
#define NCHUNK 32
#define LCHUNK 64         // T_/NCHUNK

using bf16x8 = __attribute__((ext_vector_type(8))) short;
using f32x4  = __attribute__((ext_vector_type(4))) float;

__device__ __forceinline__ unsigned short f2bf(float f) {
    union { float f; uint32_t u; } x; x.f = f;
    uint32_t u = x.u;
    uint32_t r = (u + 0x7fffu + ((u >> 16) & 1u)) >> 16;
    return (unsigned short)r;
}
__device__ __forceinline__ float bf2f(unsigned short h) {
    union { uint32_t u; float f; } x; x.u = ((uint32_t)h) << 16;
    return x.f;
}
__device__ __forceinline__ float sigm(float v) { return 1.0f / (1.0f + expf(-v)); }
__device__ __forceinline__ float silu(float v) { return v / (1.0f + expf(-v)); }

__device__ __forceinline__ void gload_lds16(const void* g, void* l) {
    __builtin_amdgcn_global_load_lds(
        (__attribute__((address_space(1))) void*)(void*)g,
        (__attribute__((address_space(3))) void*)l, 16, 0, 0);
}

// ---------------- transpose + bf16 hi/lo split: W[K][N] -> T{h,l}[N][K] ----------------
__global__ __launch_bounds__(256)
void transpose_split(const float* __restrict__ W, unsigned short* __restrict__ Th,
                     unsigned short* __restrict__ Tl, int K, int N) {
    __shared__ float tile[32][33];
    int n0 = blockIdx.x * 32, k0 = blockIdx.y * 32;
    int tx = threadIdx.x & 31, ty = threadIdx.x >> 5;   // ty 0..7
#pragma unroll
    for (int i = 0; i < 32; i += 8)
        tile[ty + i][tx] = W[(size_t)(k0 + ty + i) * N + (n0 + tx)];
    __syncthreads();
#pragma unroll
    for (int i = 0; i < 32; i += 8) {
        float v = tile[tx][ty + i];
        size_t o = (size_t)(n0 + ty + i) * K + (k0 + tx);
        unsigned short h = f2bf(v);
        Th[o] = h;
        Tl[o] = f2bf(v - bf2f(h));
    }
}

// ---------------- RMSNorm -> single bf16 ----------------
__global__ __launch_bounds__(256)
void rmsnorm_bf(const float* __restrict__ x, const float* __restrict__ w,
                unsigned short* __restrict__ xh) {
    int row = blockIdx.x;            // 0..4095
    int tid = threadIdx.x;
    const float4* xr = (const float4*)(x + (size_t)row * H_);
    float4 v = xr[tid];
    float ss = v.x * v.x + v.y * v.y + v.z * v.z + v.w * v.w;
#pragma unroll
    for (int o = 32; o > 0; o >>= 1) ss += __shfl_down(ss, o, 64);
    __shared__ float red[4];
    int lane = tid & 63, wv = tid >> 6;
    if (lane == 0) red[wv] = ss;
    __syncthreads();
    float tot = red[0] + red[1] + red[2] + red[3];
    float rstd = rsqrtf(tot / (float)H_ + 1e-6f);
    const float4* wr = (const float4*)w;
    float4 w4 = wr[tid];
    size_t o = (size_t)row * H_ + tid * 4;
    *(ushort4*)&xh[o] = make_ushort4(f2bf(v.x * rstd * w4.x), f2bf(v.y * rstd * w4.y),
                                     f2bf(v.z * rstd * w4.z), f2bf(v.w * rstd * w4.w));
}

// ---------------- bf16x2 split GEMM: C = A_bf16 @ (Bh+Bl)^T, 128x128 tile ----------------
// EPI 0: xz epilogue -> silu; col<2048: x_in bf16 -> oh, else silu_z bf16 -> oz
// EPI 1: a_mod = sigmoid(acc + aux[col]) -> out0 (fp32)
// EPI 2: out0 = acc + aux[row*N+col]   (residual add, fp32)
template <int EPI>
__global__ __launch_bounds__(256)
void gemm_x2(const unsigned short* __restrict__ Aa,
             const unsigned short* __restrict__ Bh, const unsigned short* __restrict__ Bl,
             int N, int K,
             float* __restrict__ out0,
             unsigned short* __restrict__ oh, unsigned short* __restrict__ oz,
             const float* __restrict__ aux) {
    __shared__ unsigned short sm[3 * 4096];   // A, Bh, Bl tiles: 128x32 bf16 = 8KB each
    const int tid  = threadIdx.x;
    const int lane = tid & 63;
    const int wid  = tid >> 6;
    const int wm   = wid >> 1, wn = wid & 1;
    const int bm   = blockIdx.y * 128;
    const int bn   = blockIdx.x * 128;
    const int lrow = lane >> 2;          // 0..15 within 16-row chunk
    const int lcol = (lane & 3) * 8;     // bf16 element offset (16B granules)

    // 24 stage units (3 matrices x 8 chunks of 16 rows); 6 per wave
    const unsigned short* b0 = Aa + (size_t)bm * K;
    const unsigned short* b1 = Bh + (size_t)bn * K;
    const unsigned short* b2 = Bl + (size_t)bn * K;
    const unsigned short* gp[6];
    unsigned short* lp[6];
#pragma unroll
    for (int j = 0; j < 6; ++j) {
        int u = wid * 6 + j;
        int mat = u >> 3, chunk = u & 7;
        const unsigned short* base = (mat == 0) ? b0 : ((mat == 1) ? b1 : b2);
        gp[j] = base + (size_t)(chunk * 16 + lrow) * K + lcol;
        lp[j] = &sm[mat * 4096 + chunk * 512];
    }

    f32x4 acc[4][4] = {};
    const int nk = K >> 5;
    for (int kt = 0; kt < nk; ++kt) {
#pragma unroll
        for (int j = 0; j < 6; ++j)
            gload_lds16(gp[j] + kt * 32, lp[j]);
        __syncthreads();   // drains vmcnt(0): LDS tiles ready

        const int kofs = (lane >> 4) * 8;
        const int lr   = lane & 15;
        bf16x8 af[4], bh8[4], bl8[4];
#pragma unroll
        for (int m = 0; m < 4; ++m)
            af[m] = *(const bf16x8*)&sm[(wm * 64 + m * 16 + lr) * 32 + kofs];
#pragma unroll
        for (int n = 0; n < 4; ++n) {
            bh8[n] = *(const bf16x8*)&sm[4096 + (wn * 64 + n * 16 + lr) * 32 + kofs];
            bl8[n] = *(const bf16x8*)&sm[8192 + (wn * 64 + n * 16 + lr) * 32 + kofs];
        }
#pragma unroll
        for (int m = 0; m < 4; ++m)
#pragma unroll
            for (int n = 0; n < 4; ++n) {
                acc[m][n] = __builtin_amdgcn_mfma_f32_16x16x32_bf16(af[m], bh8[n], acc[m][n], 0, 0, 0);
                acc[m][n] = __builtin_amdgcn_mfma_f32_16x16x32_bf16(af[m], bl8[n], acc[m][n], 0, 0, 0);
            }
        __syncthreads();   // protect LDS before next stage
    }

    // epilogue: C/D layout col=lane&15, row=(lane>>4)*4+reg  [m89-verified]
#pragma unroll
    for (int m = 0; m < 4; ++m)
#pragma unroll
        for (int n = 0; n < 4; ++n) {
            int col  = bn + wn * 64 + n * 16 + (lane & 15);
            int row0 = bm + wm * 64 + m * 16 + ((lane >> 4) << 2);
#pragma unroll
            for (int r = 0; r < 4; ++r) {
                int row = row0 + r;
                float v = acc[m][n][r];
                if (EPI == 0) {
                    float s = silu(v);
                    if (col < DIN_) oh[(size_t)row * DIN_ + col] = f2bf(s);
                    else            oz[(size_t)row * DIN_ + (col - DIN_)] = f2bf(s);
                } else if (EPI == 1) {
                    out0[(size_t)row * N + col] = sigm(v + aux[col]);
                } else {
                    out0[(size_t)row * N + col] = v + aux[(size_t)row * N + col];
                }
            }
        }
}

// ---------------- B_in / C_in projections (N=16 each) ----------------
__global__ __launch_bounds__(256)
void bc_proj(const unsigned short* __restrict__ xh,
             const float* __restrict__ Bw, const float* __restrict__ Cw,
             float* __restrict__ Bout, float* __restrict__ Cout) {
    int m = blockIdx.x;
    int tid = threadIdx.x;
    float ab[16], ac[16];
#pragma unroll
    for (int i = 0; i < 16; ++i) { ab[i] = 0.f; ac[i] = 0.f; }
    for (int k = tid; k < DIN_; k += 256) {
        float x = bf2f(xh[(size_t)m * DIN_ + k]);
        const float4* br = (const float4*)(Bw + (size_t)k * 16);
        const float4* cr = (const float4*)(Cw + (size_t)k * 16);
#pragma unroll
        for (int j = 0; j < 4; ++j) {
            float4 b4 = br[j], c4 = cr[j];
            ab[j * 4 + 0] = fmaf(x, b4.x, ab[j * 4 + 0]);
            ab[j * 4 + 1] = fmaf(x, b4.y, ab[j * 4 + 1]);
            ab[j * 4 + 2] = fmaf(x, b4.z, ab[j * 4 + 2]);
            ab[j * 4 + 3] = fmaf(x, b4.w, ab[j * 4 + 3]);
            ac[j * 4 + 0] = fmaf(x, c4.x, ac[j * 4 + 0]);
            ac[j * 4 + 1] = fmaf(x, c4.y, ac[j * 4 + 1]);
            ac[j * 4 + 2] = fmaf(x, c4.z, ac[j * 4 + 2]);
            ac[j * 4 + 3] = fmaf(x, c4.w, ac[j * 4 + 3]);
        }
    }
    int lane = tid & 63, w = tid >> 6;
#pragma unroll
    for (int i = 0; i < 16; ++i)
#pragma unroll
        for (int o = 32; o > 0; o >>= 1) {
            ab[i] += __shfl_down(ab[i], o, 64);
            ac[i] += __shfl_down(ac[i], o, 64);
        }
    __shared__ float rb[4][16], rc[4][16];
    if (lane == 0) {
#pragma unroll
        for (int i = 0; i < 16; ++i) { rb[w][i] = ab[i]; rc[w][i] = ac[i]; }
    }
    __syncthreads();
    if (tid < 16) {
        Bout[(size_t)m * 16 + tid] = rb[0][tid] + rb[1][tid] + rb[2][tid] + rb[3][tid];
        Cout[(size_t)m * 16 + tid] = rc[0][tid] + rc[1][tid] + rc[2][tid] + rc[3][tid];
    }
}

// ---------------- chunked parallel scan ----------------
__global__ __launch_bounds__(256)
void scan_phase1(const float* __restrict__ amod, const unsigned short* __restrict__ xh,
                 const float* __restrict__ Bin, const float* __restrict__ Abase,
                 float* __restrict__ P, float* __restrict__ S) {
    int d = blockIdx.x * 256 + threadIdx.x;   // 0..2047
    int c = blockIdx.y;
    int b = blockIdx.z;
    float ab[16];
#pragma unroll
    for (int n = 0; n < 16; ++n) ab[n] = sigm(Abase[n]);
    float p[16], s[16];
#pragma unroll
    for (int n = 0; n < 16; ++n) { p[n] = 1.0f; s[n] = 0.0f; }
    int t0 = c * LCHUNK;
    for (int tt = 0; tt < LCHUNK; ++tt) {
        size_t mrow = (size_t)(b * T_ + t0 + tt);
        float a = amod[mrow * DIN_ + d];
        float x = bf2f(xh[mrow * DIN_ + d]);
        const float4* bt4 = (const float4*)(Bin + mrow * 16);
        float4 q0 = bt4[0], q1 = bt4[1], q2 = bt4[2], q3 = bt4[3];
        float bt[16];
        bt[0]=q0.x; bt[1]=q0.y; bt[2]=q0.z; bt[3]=q0.w;
        bt[4]=q1.x; bt[5]=q1.y; bt[6]=q1.z; bt[7]=q1.w;
        bt[8]=q2.x; bt[9]=q2.y; bt[10]=q2.z; bt[11]=q2.w;
        bt[12]=q3.x; bt[13]=q3.y; bt[14]=q3.z; bt[15]=q3.w;
#pragma unroll
        for (int n = 0; n < 16; ++n) {
            float dk = a * ab[n];
            p[n] *= dk;
            s[n] = fmaf(dk, s[n], bt[n] * x);
        }
    }
    size_t base = ((size_t)(b * NCHUNK + c) << 15) + (size_t)d * 16;
    float4* P4 = (float4*)(P + base);
    float4* S4 = (float4*)(S + base);
#pragma unroll
    for (int j = 0; j < 4; ++j) {
        P4[j] = make_float4(p[4*j], p[4*j+1], p[4*j+2], p[4*j+3]);
        S4[j] = make_float4(s[4*j], s[4*j+1], s[4*j+2], s[4*j+3]);
    }
}

__global__ __launch_bounds__(256)
void scan_phase2(const float* __restrict__ P, const float* __restrict__ S,
                 float* __restrict__ H0) {
    int idx = blockIdx.x * 256 + threadIdx.x;   // 0..65535
    int b = idx >> 15;
    int dn = idx & 32767;
    float g = 0.f;
    for (int c = 0; c < NCHUNK; ++c) {
        size_t base = ((size_t)(b * NCHUNK + c) << 15) + dn;
        H0[base] = g;
        g = fmaf(P[base], g, S[base]);
    }
}

__global__ __launch_bounds__(256)
void scan_phase3(const float* __restrict__ amod, const unsigned short* __restrict__ xh,
                 const float* __restrict__ Bin, const float* __restrict__ Cin,
                 const float* __restrict__ Abase, const float* __restrict__ H0,
                 const float* __restrict__ Dp, const unsigned short* __restrict__ szh,
                 unsigned short* __restrict__ yh) {
    int d = blockIdx.x * 256 + threadIdx.x;
    int c = blockIdx.y;
    int b = blockIdx.z;
    float ab[16];
#pragma unroll
    for (int n = 0; n < 16; ++n) ab[n] = sigm(Abase[n]);
    float h[16];
    size_t hbase = ((size_t)(b * NCHUNK + c) << 15) + (size_t)d * 16;
    const float4* H4 = (const float4*)(H0 + hbase);
#pragma unroll
    for (int j = 0; j < 4; ++j) {
        float4 t4 = H4[j];
        h[j*4] = t4.x; h[j*4+1] = t4.y; h[j*4+2] = t4.z; h[j*4+3] = t4.w;
    }
    float Dd = Dp[d];
    int t0 = c * LCHUNK;
    for (int tt = 0; tt < LCHUNK; ++tt) {
        size_t mrow = (size_t)(b * T_ + t0 + tt);
        float a = amod[mrow * DIN_ + d];
        float x = bf2f(xh[mrow * DIN_ + d]);
        const float4* bt4 = (const float4*)(Bin + mrow * 16);
        const float4* ct4 = (const float4*)(Cin + mrow * 16);
        float4 q0 = bt4[0], q1 = bt4[1], q2 = bt4[2], q3 = bt4[3];
        float4 r0 = ct4[0], r1 = ct4[1], r2 = ct4[2], r3 = ct4[3];
        float bt[16], ct[16];
        bt[0]=q0.x; bt[1]=q0.y; bt[2]=q0.z; bt[3]=q0.w;
        bt[4]=q1.x; bt[5]=q1.y; bt[6]=q1.z; bt[7]=q1.w;
        bt[8]=q2.x; bt[9]=q2.y; bt[10]=q2.z; bt[11]=q2.w;
        bt[12]=q3.x; bt[13]=q3.y; bt[14]=q3.z; bt[15]=q3.w;
        ct[0]=r0.x; ct[1]=r0.y; ct[2]=r0.z; ct[3]=r0.w;
        ct[4]=r1.x; ct[5]=r1.y; ct[6]=r1.z; ct[7]=r1.w;
        ct[8]=r2.x; ct[9]=r2.y; ct[10]=r2.z; ct[11]=r2.w;
        ct[12]=r3.x; ct[13]=r3.y; ct[14]=r3.z; ct[15]=r3.w;
        float y = 0.f;
#pragma unroll
        for (int n = 0; n < 16; ++n) {
            float dk = a * ab[n];
            h[n] = fmaf(dk, h[n], bt[n] * x);
            y = fmaf(h[n], ct[n], y);
        }
        float val = (y + Dd * x) * bf2f(szh[mrow * DIN_ + d]);
        yh[mrow * DIN_ + d] = f2bf(val);
    }
}

// ---------------- launch ----------------
extern "C" void kernel_launch(void* const* d_in, const int* in_sizes, int n_in,
                              void* d_out, int out_size, void* d_ws, size_t ws_size,
                              hipStream_t stream) {
    const float* x          = (const float*)d_in[0];
    const float* norm_w     = (const float*)d_in[1];
    const float* in_proj_w  = (const float*)d_in[2];
    const float* A_proj_w   = (const float*)d_in[3];
    const float* A_proj_b   = (const float*)d_in[4];
    const float* A_base     = (const float*)d_in[5];
    const float* B_proj_w   = (const float*)d_in[6];
    const float* C_proj_w   = (const float*)d_in[7];
    const float* Dp         = (const float*)d_in[8];
    const float* out_proj_w = (const float*)d_in[9];
    float* out = (float*)d_out;

    char* ws = (char*)d_ws;
    size_t off = 0;
    auto alloc = [&](size_t bytes) -> char* {
        char* p = ws + off;
        off += (bytes + 255) & ~(size_t)255;
        return p;
    };
    unsigned short* inTh = (unsigned short*)alloc((size_t)4096 * 1024 * 2);
    unsigned short* inTl = (unsigned short*)alloc((size_t)4096 * 1024 * 2);
    unsigned short* ATh  = (unsigned short*)alloc((size_t)2048 * 2048 * 2);
    unsigned short* ATl  = (unsigned short*)alloc((size_t)2048 * 2048 * 2);
    unsigned short* OTh  = (unsigned short*)alloc((size_t)1024 * 2048 * 2);
    unsigned short* OTl  = (unsigned short*)alloc((size_t)1024 * 2048 * 2);
    unsigned short* xnh  = (unsigned short*)alloc((size_t)M_ * H_ * 2);
    unsigned short* xinh = (unsigned short*)alloc((size_t)M_ * DIN_ * 2);
    unsigned short* szh  = (unsigned short*)alloc((size_t)M_ * DIN_ * 2);
    float* amod   = (float*)alloc((size_t)M_ * DIN_ * 4);
    float* Bin    = (float*)alloc((size_t)M_ * 16 * 4);
    float* Cin    = (float*)alloc((size_t)M_ * 16 * 4);
    float* Pw     = (float*)alloc((size_t)B_ * NCHUNK * DIN_ * NS_ * 4);
    float* Sw     = (float*)alloc((size_t)B_ * NCHUNK * DIN_ * NS_ * 4);
    float* H0w    = (float*)alloc((size_t)B_ * NCHUNK * DIN_ * NS_ * 4);
    unsigned short* yh = (unsigned short*)alloc((size_t)M_ * DIN_ * 2);
    (void)ws_size;

    // weight prep: transpose + split (weights keep h+l; activations are plain bf16)
    transpose_split<<<dim3(4096 / 32, 1024 / 32), 256, 0, stream>>>(in_proj_w, inTh, inTl, 1024, 4096);
    transpose_split<<<dim3(2048 / 32, 2048 / 32), 256, 0, stream>>>(A_proj_w, ATh, ATl, 2048, 2048);
    transpose_split<<<dim3(1024 / 32, 2048 / 32), 256, 0, stream>>>(out_proj_w, OTh, OTl, 2048, 1024);

    rmsnorm_bf<<<M_, 256, 0, stream>>>(x, norm_w, xnh);

    // xz = xn @ in_proj  (M=4096, N=4096, K=1024) -> x_in bf16 + silu_z bf16
    gemm_x2<0><<<dim3(4096 / 128, M_ / 128), 256, 0, stream>>>(
        xnh, inTh, inTl, 4096, 1024, nullptr, xinh, szh, nullptr);

    // a_mod = sigmoid(x_in @ A_proj + b)  (N=2048, K=2048) -> fp32
    gemm_x2<1><<<dim3(2048 / 128, M_ / 128), 256, 0, stream>>>(
        xinh, ATh, ATl, 2048, 2048, amod, nullptr, nullptr, A_proj_b);

    // B_in, C_in
    bc_proj<<<M_, 256, 0, stream>>>(xinh, B_proj_w, C_proj_w, Bin, Cin);

    // chunked scan
    scan_phase1<<<dim3(DIN_ / 256, NCHUNK, B_), 256, 0, stream>>>(amod, xinh, Bin, A_base, Pw, Sw);
    scan_phase2<<<(B_ * DIN_ * NS_) / 256, 256, 0, stream>>>(Pw, Sw, H0w);
    scan_phase3<<<dim3(DIN_ / 256, NCHUNK, B_), 256, 0, stream>>>(
        amod, xinh, Bin, Cin, A_base, H0w, Dp, szh, yh);

    // out = residual + y @ out_proj  (N=1024, K=2048)
    gemm_x2<2><<<dim3(1024 / 128, M_ / 128), 256, 0, stream>>>(
        yh, OTh, OTl, 1024, 2048, out, nullptr, nullptr, x);
}

// Round 3
// 384.361 us; speedup vs baseline: 1.3168x; 1.1209x over previous
//
#include <hip/hip_runtime.h>
#include <cstdint>

#define B_    2
#define T_    2048
#define H_    1024
#define DIN_  2048
#define NS_   16
#define M_    (B_*T_)     // 4096
#define NCHUNK 32
#define LCHUNK 64         // T_/NCHUNK

using bf16x8 = __attribute__((ext_vector_type(8))) short;
using f32x4  = __attribute__((ext_vector_type(4))) float;

__device__ __forceinline__ unsigned short f2bf(float f) {
    union { float f; uint32_t u; } x; x.f = f;
    uint32_t u = x.u;
    uint32_t r = (u + 0x7fffu + ((u >> 16) & 1u)) >> 16;
    return (unsigned short)r;
}
__device__ __forceinline__ float bf2f(unsigned short h) {
    union { uint32_t u; float f; } x; x.u = ((uint32_t)h) << 16;
    return x.f;
}
__device__ __forceinline__ float sigm(float v) { return 1.0f / (1.0f + expf(-v)); }
__device__ __forceinline__ float silu(float v) { return v / (1.0f + expf(-v)); }

__device__ __forceinline__ void gload_lds16(const void* g, void* l) {
    __builtin_amdgcn_global_load_lds(
        (__attribute__((address_space(1))) void*)(void*)g,
        (__attribute__((address_space(3))) void*)l, 16, 0, 0);
}

// ---------------- transpose + bf16 hi/lo split: W[K][N] -> T{h,l}[N][K] ----------------
__global__ __launch_bounds__(256)
void transpose_split(const float* __restrict__ W, unsigned short* __restrict__ Th,
                     unsigned short* __restrict__ Tl, int K, int N) {
    __shared__ float tile[32][33];
    int n0 = blockIdx.x * 32, k0 = blockIdx.y * 32;
    int tx = threadIdx.x & 31, ty = threadIdx.x >> 5;   // ty 0..7
#pragma unroll
    for (int i = 0; i < 32; i += 8)
        tile[ty + i][tx] = W[(size_t)(k0 + ty + i) * N + (n0 + tx)];
    __syncthreads();
    int sx = (threadIdx.x & 15) * 2;   // k offset, even
    int sy = threadIdx.x >> 4;         // n 0..15
#pragma unroll
    for (int i = 0; i < 32; i += 16) {
        int n = sy + i;
        float v0 = tile[sx][n], v1 = tile[sx + 1][n];
        size_t o = (size_t)(n0 + n) * K + (k0 + sx);
        unsigned short h0 = f2bf(v0), h1 = f2bf(v1);
        *(ushort2*)&Th[o] = make_ushort2(h0, h1);
        *(ushort2*)&Tl[o] = make_ushort2(f2bf(v0 - bf2f(h0)), f2bf(v1 - bf2f(h1)));
    }
}

// ---------------- RMSNorm -> single bf16 ----------------
__global__ __launch_bounds__(256)
void rmsnorm_bf(const float* __restrict__ x, const float* __restrict__ w,
                unsigned short* __restrict__ xh) {
    int row = blockIdx.x;            // 0..4095
    int tid = threadIdx.x;
    const float4* xr = (const float4*)(x + (size_t)row * H_);
    float4 v = xr[tid];
    float ss = v.x * v.x + v.y * v.y + v.z * v.z + v.w * v.w;
#pragma unroll
    for (int o = 32; o > 0; o >>= 1) ss += __shfl_down(ss, o, 64);
    __shared__ float red[4];
    int lane = tid & 63, wv = tid >> 6;
    if (lane == 0) red[wv] = ss;
    __syncthreads();
    float tot = red[0] + red[1] + red[2] + red[3];
    float rstd = rsqrtf(tot / (float)H_ + 1e-6f);
    const float4* wr = (const float4*)w;
    float4 w4 = wr[tid];
    size_t o = (size_t)row * H_ + tid * 4;
    *(ushort4*)&xh[o] = make_ushort4(f2bf(v.x * rstd * w4.x), f2bf(v.y * rstd * w4.y),
                                     f2bf(v.z * rstd * w4.z), f2bf(v.w * rstd * w4.w));
}

// ---------------- bf16x2 split GEMM: C = A_bf16 @ (Bh+Bl)^T, 128x128 tile ----------------
// 3-buffer pipelined K-loop (counted vmcnt) + XOR-swizzled LDS (T2/T3/T4).
// EPI 0: xz epilogue -> silu; col<2048: x_in bf16 -> oh, else silu_z bf16 -> oz
// EPI 1: a_mod = sigmoid(acc + aux[col]) -> out0 (fp32)
// EPI 2: out0 = acc + aux[row*N+col]   (residual add, fp32)
template <int EPI>
__global__ __launch_bounds__(256)
void gemm_x2(const unsigned short* __restrict__ Aa,
             const unsigned short* __restrict__ Bh, const unsigned short* __restrict__ Bl,
             int N, int K,
             float* __restrict__ out0,
             unsigned short* __restrict__ oh, unsigned short* __restrict__ oz,
             const float* __restrict__ aux) {
    __shared__ unsigned short sm[3][3 * 4096];   // 3 buffers x (A,Bh,Bl 128x32 tiles) = 72KB
    const int tid  = threadIdx.x;
    const int lane = tid & 63;
    const int wid  = tid >> 6;
    const int wm   = wid >> 1, wn = wid & 1;
    const int bm   = blockIdx.y * 128;
    const int bn   = blockIdx.x * 128;

    // staging: 24 units (3 mats x 8 chunks of 16 rows); 6 per wave.
    // swizzle: data (row r, granule c) -> LDS slot (r, c ^ (r&3)); achieved by
    // pre-swizzling the per-lane GLOBAL source (linear LDS dest, rule 21).
    const unsigned short* b0 = Aa + (size_t)bm * K;
    const unsigned short* b1 = Bh + (size_t)bn * K;
    const unsigned short* b2 = Bl + (size_t)bn * K;
    const int lrow = lane >> 2;                        // 0..15 within chunk
    const int scol = ((lane & 3) ^ (lrow & 3)) * 8;    // swizzled source granule (elems)
    const unsigned short* gp[6];
    int lofs[6];
#pragma unroll
    for (int j = 0; j < 6; ++j) {
        int u = wid * 6 + j;
        int mat = u >> 3, chunk = u & 7;
        const unsigned short* base = (mat == 0) ? b0 : ((mat == 1) ? b1 : b2);
        gp[j] = base + (size_t)(chunk * 16 + lrow) * K + scol;
        lofs[j] = mat * 4096 + chunk * 512;
    }

    const int nk = K >> 5;
    // prologue: stage tiles 0,1 into buffers 0,1 (12 loads in flight)
#pragma unroll
    for (int j = 0; j < 6; ++j) gload_lds16(gp[j], &sm[0][lofs[j]]);
#pragma unroll
    for (int j = 0; j < 6; ++j) gload_lds16(gp[j] + 32, &sm[1][lofs[j]]);

    const int lr = lane & 15;
    const int sw = (((lane >> 4) ^ (lr & 3)) * 8);     // swizzled read granule (elems)
    const int arow = wm * 4;
    const int brow = wn * 4;

    f32x4 acc[4][4] = {};
    int bsel = 0;
    for (int kt = 0; kt < nk; ++kt) {
        // tile kt's 6 loads are the oldest; tile kt+1's 6 may stay in flight
        if (kt + 1 < nk) asm volatile("s_waitcnt vmcnt(6)" ::: "memory");
        else             asm volatile("s_waitcnt vmcnt(0)" ::: "memory");
        __builtin_amdgcn_s_barrier();
        __builtin_amdgcn_sched_barrier(0);
        if (kt + 2 < nk) {      // stage tile kt+2 into buffer of tile kt-1
            int nb = bsel + 2; if (nb >= 3) nb -= 3;
#pragma unroll
            for (int j = 0; j < 6; ++j)
                gload_lds16(gp[j] + (kt + 2) * 32, &sm[nb][lofs[j]]);
        }
        const unsigned short* sb = sm[bsel];
        bf16x8 af[4], bh8[4], bl8[4];
#pragma unroll
        for (int m = 0; m < 4; ++m)
            af[m] = *(const bf16x8*)&sb[(arow + m) * 512 + lr * 32 + sw];
#pragma unroll
        for (int n = 0; n < 4; ++n) {
            bh8[n] = *(const bf16x8*)&sb[4096 + (brow + n) * 512 + lr * 32 + sw];
            bl8[n] = *(const bf16x8*)&sb[8192 + (brow + n) * 512 + lr * 32 + sw];
        }
#pragma unroll
        for (int m = 0; m < 4; ++m)
#pragma unroll
            for (int n = 0; n < 4; ++n) {
                acc[m][n] = __builtin_amdgcn_mfma_f32_16x16x32_bf16(af[m], bh8[n], acc[m][n], 0, 0, 0);
                acc[m][n] = __builtin_amdgcn_mfma_f32_16x16x32_bf16(af[m], bl8[n], acc[m][n], 0, 0, 0);
            }
        bsel += 1; if (bsel == 3) bsel = 0;
    }

    // epilogue: C/D layout col=lane&15, row=(lane>>4)*4+reg  [m89-verified]
#pragma unroll
    for (int m = 0; m < 4; ++m)
#pragma unroll
        for (int n = 0; n < 4; ++n) {
            int col  = bn + wn * 64 + n * 16 + (lane & 15);
            int row0 = bm + wm * 64 + m * 16 + ((lane >> 4) << 2);
#pragma unroll
            for (int r = 0; r < 4; ++r) {
                int row = row0 + r;
                float v = acc[m][n][r];
                if (EPI == 0) {
                    float s = silu(v);
                    if (col < DIN_) oh[(size_t)row * DIN_ + col] = f2bf(s);
                    else            oz[(size_t)row * DIN_ + (col - DIN_)] = f2bf(s);
                } else if (EPI == 1) {
                    out0[(size_t)row * N + col] = sigm(v + aux[col]);
                } else {
                    out0[(size_t)row * N + col] = v + aux[(size_t)row * N + col];
                }
            }
        }
}

// ---------------- B_in / C_in projections (N=16 each) ----------------
__global__ __launch_bounds__(256)
void bc_proj(const unsigned short* __restrict__ xh,
             const float* __restrict__ Bw, const float* __restrict__ Cw,
             float* __restrict__ Bout, float* __restrict__ Cout) {
    int m = blockIdx.x;
    int tid = threadIdx.x;
    float ab[16], ac[16];
#pragma unroll
    for (int i = 0; i < 16; ++i) { ab[i] = 0.f; ac[i] = 0.f; }
    for (int k = tid; k < DIN_; k += 256) {
        float x = bf2f(xh[(size_t)m * DIN_ + k]);
        const float4* br = (const float4*)(Bw + (size_t)k * 16);
        const float4* cr = (const float4*)(Cw + (size_t)k * 16);
#pragma unroll
        for (int j = 0; j < 4; ++j) {
            float4 b4 = br[j], c4 = cr[j];
            ab[j * 4 + 0] = fmaf(x, b4.x, ab[j * 4 + 0]);
            ab[j * 4 + 1] = fmaf(x, b4.y, ab[j * 4 + 1]);
            ab[j * 4 + 2] = fmaf(x, b4.z, ab[j * 4 + 2]);
            ab[j * 4 + 3] = fmaf(x, b4.w, ab[j * 4 + 3]);
            ac[j * 4 + 0] = fmaf(x, c4.x, ac[j * 4 + 0]);
            ac[j * 4 + 1] = fmaf(x, c4.y, ac[j * 4 + 1]);
            ac[j * 4 + 2] = fmaf(x, c4.z, ac[j * 4 + 2]);
            ac[j * 4 + 3] = fmaf(x, c4.w, ac[j * 4 + 3]);
        }
    }
    int lane = tid & 63, w = tid >> 6;
#pragma unroll
    for (int i = 0; i < 16; ++i)
#pragma unroll
        for (int o = 32; o > 0; o >>= 1) {
            ab[i] += __shfl_down(ab[i], o, 64);
            ac[i] += __shfl_down(ac[i], o, 64);
        }
    __shared__ float rb[4][16], rc[4][16];
    if (lane == 0) {
#pragma unroll
        for (int i = 0; i < 16; ++i) { rb[w][i] = ab[i]; rc[w][i] = ac[i]; }
    }
    __syncthreads();
    if (tid < 16) {
        Bout[(size_t)m * 16 + tid] = rb[0][tid] + rb[1][tid] + rb[2][tid] + rb[3][tid];
        Cout[(size_t)m * 16 + tid] = rc[0][tid] + rc[1][tid] + rc[2][tid] + rc[3][tid];
    }
}

// ---------------- chunked parallel scan ----------------
__global__ __launch_bounds__(256)
void scan_phase1(const float* __restrict__ amod, const unsigned short* __restrict__ xh,
                 const float* __restrict__ Bin, const float* __restrict__ Abase,
                 float* __restrict__ P, float* __restrict__ S) {
    int d = blockIdx.x * 256 + threadIdx.x;   // 0..2047
    int c = blockIdx.y;
    int b = blockIdx.z;
    float ab[16];
#pragma unroll
    for (int n = 0; n < 16; ++n) ab[n] = sigm(Abase[n]);
    float p[16], s[16];
#pragma unroll
    for (int n = 0; n < 16; ++n) { p[n] = 1.0f; s[n] = 0.0f; }
    int t0 = c * LCHUNK;
    for (int tt = 0; tt < LCHUNK; ++tt) {
        size_t mrow = (size_t)(b * T_ + t0 + tt);
        float a = amod[mrow * DIN_ + d];
        float x = bf2f(xh[mrow * DIN_ + d]);
        const float4* bt4 = (const float4*)(Bin + mrow * 16);
        float4 q0 = bt4[0], q1 = bt4[1], q2 = bt4[2], q3 = bt4[3];
        float bt[16];
        bt[0]=q0.x; bt[1]=q0.y; bt[2]=q0.z; bt[3]=q0.w;
        bt[4]=q1.x; bt[5]=q1.y; bt[6]=q1.z; bt[7]=q1.w;
        bt[8]=q2.x; bt[9]=q2.y; bt[10]=q2.z; bt[11]=q2.w;
        bt[12]=q3.x; bt[13]=q3.y; bt[14]=q3.z; bt[15]=q3.w;
#pragma unroll
        for (int n = 0; n < 16; ++n) {
            float dk = a * ab[n];
            p[n] *= dk;
            s[n] = fmaf(dk, s[n], bt[n] * x);
        }
    }
    size_t base = ((size_t)(b * NCHUNK + c) << 15) + (size_t)d * 16;
    float4* P4 = (float4*)(P + base);
    float4* S4 = (float4*)(S + base);
#pragma unroll
    for (int j = 0; j < 4; ++j) {
        P4[j] = make_float4(p[4*j], p[4*j+1], p[4*j+2], p[4*j+3]);
        S4[j] = make_float4(s[4*j], s[4*j+1], s[4*j+2], s[4*j+3]);
    }
}

__global__ __launch_bounds__(256)
void scan_phase2(const float* __restrict__ P, const float* __restrict__ S,
                 float* __restrict__ H0) {
    int idx = blockIdx.x * 256 + threadIdx.x;   // 0..65535
    int b = idx >> 15;
    int dn = idx & 32767;
    float g = 0.f;
    for (int c = 0; c < NCHUNK; ++c) {
        size_t base = ((size_t)(b * NCHUNK + c) << 15) + dn;
        H0[base] = g;
        g = fmaf(P[base], g, S[base]);
    }
}

__global__ __launch_bounds__(256)
void scan_phase3(const float* __restrict__ amod, const unsigned short* __restrict__ xh,
                 const float* __restrict__ Bin, const float* __restrict__ Cin,
                 const float* __restrict__ Abase, const float* __restrict__ H0,
                 const float* __restrict__ Dp, const unsigned short* __restrict__ szh,
                 unsigned short* __restrict__ yh) {
    int d = blockIdx.x * 256 + threadIdx.x;
    int c = blockIdx.y;
    int b = blockIdx.z;
    float ab[16];
#pragma unroll
    for (int n = 0; n < 16; ++n) ab[n] = sigm(Abase[n]);
    float h[16];
    size_t hbase = ((size_t)(b * NCHUNK + c) << 15) + (size_t)d * 16;
    const float4* H4 = (const float4*)(H0 + hbase);
#pragma unroll
    for (int j = 0; j < 4; ++j) {
        float4 t4 = H4[j];
        h[j*4] = t4.x; h[j*4+1] = t4.y; h[j*4+2] = t4.z; h[j*4+3] = t4.w;
    }
    float Dd = Dp[d];
    int t0 = c * LCHUNK;
    for (int tt = 0; tt < LCHUNK; ++tt) {
        size_t mrow = (size_t)(b * T_ + t0 + tt);
        float a = amod[mrow * DIN_ + d];
        float x = bf2f(xh[mrow * DIN_ + d]);
        const float4* bt4 = (const float4*)(Bin + mrow * 16);
        const float4* ct4 = (const float4*)(Cin + mrow * 16);
        float4 q0 = bt4[0], q1 = bt4[1], q2 = bt4[2], q3 = bt4[3];
        float4 r0 = ct4[0], r1 = ct4[1], r2 = ct4[2], r3 = ct4[3];
        float bt[16], ct[16];
        bt[0]=q0.x; bt[1]=q0.y; bt[2]=q0.z; bt[3]=q0.w;
        bt[4]=q1.x; bt[5]=q1.y; bt[6]=q1.z; bt[7]=q1.w;
        bt[8]=q2.x; bt[9]=q2.y; bt[10]=q2.z; bt[11]=q2.w;
        bt[12]=q3.x; bt[13]=q3.y; bt[14]=q3.z; bt[15]=q3.w;
        ct[0]=r0.x; ct[1]=r0.y; ct[2]=r0.z; ct[3]=r0.w;
        ct[4]=r1.x; ct[5]=r1.y; ct[6]=r1.z; ct[7]=r1.w;
        ct[8]=r2.x; ct[9]=r2.y; ct[10]=r2.z; ct[11]=r2.w;
        ct[12]=r3.x; ct[13]=r3.y; ct[14]=r3.z; ct[15]=r3.w;
        float y = 0.f;
#pragma unroll
        for (int n = 0; n < 16; ++n) {
            float dk = a * ab[n];
            h[n] = fmaf(dk, h[n], bt[n] * x);
            y = fmaf(h[n], ct[n], y);
        }
        float val = (y + Dd * x) * bf2f(szh[mrow * DIN_ + d]);
        yh[mrow * DIN_ + d] = f2bf(val);
    }
}

// ---------------- launch ----------------
extern "C" void kernel_launch(void* const* d_in, const int* in_sizes, int n_in,
                              void* d_out, int out_size, void* d_ws, size_t ws_size,
                              hipStream_t stream) {
    const float* x          = (const float*)d_in[0];
    const float* norm_w     = (const float*)d_in[1];
    const float* in_proj_w  = (const float*)d_in[2];
    const float* A_proj_w   = (const float*)d_in[3];
    const float* A_proj_b   = (const float*)d_in[4];
    const float* A_base     = (const float*)d_in[5];
    const float* B_proj_w   = (const float*)d_in[6];
    const float* C_proj_w   = (const float*)d_in[7];
    const float* Dp         = (const float*)d_in[8];
    const float* out_proj_w = (const float*)d_in[9];
    float* out = (float*)d_out;

    char* ws = (char*)d_ws;
    size_t off = 0;
    auto alloc = [&](size_t bytes) -> char* {
        char* p = ws + off;
        off += (bytes + 255) & ~(size_t)255;
        return p;
    };
    unsigned short* inTh = (unsigned short*)alloc((size_t)4096 * 1024 * 2);
    unsigned short* inTl = (unsigned short*)alloc((size_t)4096 * 1024 * 2);
    unsigned short* ATh  = (unsigned short*)alloc((size_t)2048 * 2048 * 2);
    unsigned short* ATl  = (unsigned short*)alloc((size_t)2048 * 2048 * 2);
    unsigned short* OTh  = (unsigned short*)alloc((size_t)1024 * 2048 * 2);
    unsigned short* OTl  = (unsigned short*)alloc((size_t)1024 * 2048 * 2);
    unsigned short* xnh  = (unsigned short*)alloc((size_t)M_ * H_ * 2);
    unsigned short* xinh = (unsigned short*)alloc((size_t)M_ * DIN_ * 2);
    unsigned short* szh  = (unsigned short*)alloc((size_t)M_ * DIN_ * 2);
    float* amod   = (float*)alloc((size_t)M_ * DIN_ * 4);
    float* Bin    = (float*)alloc((size_t)M_ * 16 * 4);
    float* Cin    = (float*)alloc((size_t)M_ * 16 * 4);
    float* Pw     = (float*)alloc((size_t)B_ * NCHUNK * DIN_ * NS_ * 4);
    float* Sw     = (float*)alloc((size_t)B_ * NCHUNK * DIN_ * NS_ * 4);
    float* H0w    = (float*)alloc((size_t)B_ * NCHUNK * DIN_ * NS_ * 4);
    unsigned short* yh = (unsigned short*)alloc((size_t)M_ * DIN_ * 2);
    (void)ws_size;

    // weight prep: transpose + split (weights keep h+l; activations are plain bf16)
    transpose_split<<<dim3(4096 / 32, 1024 / 32), 256, 0, stream>>>(in_proj_w, inTh, inTl, 1024, 4096);
    transpose_split<<<dim3(2048 / 32, 2048 / 32), 256, 0, stream>>>(A_proj_w, ATh, ATl, 2048, 2048);
    transpose_split<<<dim3(1024 / 32, 2048 / 32), 256, 0, stream>>>(out_proj_w, OTh, OTl, 2048, 1024);

    rmsnorm_bf<<<M_, 256, 0, stream>>>(x, norm_w, xnh);

    // xz = xn @ in_proj  (M=4096, N=4096, K=1024) -> x_in bf16 + silu_z bf16
    gemm_x2<0><<<dim3(4096 / 128, M_ / 128), 256, 0, stream>>>(
        xnh, inTh, inTl, 4096, 1024, nullptr, xinh, szh, nullptr);

    // a_mod = sigmoid(x_in @ A_proj + b)  (N=2048, K=2048) -> fp32
    gemm_x2<1><<<dim3(2048 / 128, M_ / 128), 256, 0, stream>>>(
        xinh, ATh, ATl, 2048, 2048, amod, nullptr, nullptr, A_proj_b);

    // B_in, C_in
    bc_proj<<<M_, 256, 0, stream>>>(xinh, B_proj_w, C_proj_w, Bin, Cin);

    // chunked scan
    scan_phase1<<<dim3(DIN_ / 256, NCHUNK, B_), 256, 0, stream>>>(amod, xinh, Bin, A_base, Pw, Sw);
    scan_phase2<<<(B_ * DIN_ * NS_) / 256, 256, 0, stream>>>(Pw, Sw, H0w);
    scan_phase3<<<dim3(DIN_ / 256, NCHUNK, B_), 256, 0, stream>>>(
        amod, xinh, Bin, Cin, A_base, H0w, Dp, szh, yh);

    // out = residual + y @ out_proj  (N=1024, K=2048)
    gemm_x2<2><<<dim3(1024 / 128, M_ / 128), 256, 0, stream>>>(
        yh, OTh, OTl, 1024, 2048, out, nullptr, nullptr, x);
}

// Round 4
// 311.323 us; speedup vs baseline: 1.6257x; 1.2346x over previous
//
#include <hip/hip_runtime.h>
#include <hip/hip_fp16.h>
#include <cstdint>

#define B_    2
#define T_    2048
#define H_    1024
#define DIN_  2048
#define NS_   16
#define M_    (B_*T_)     // 4096
#define NCHUNK 32
#define LCHUNK 64         // T_/NCHUNK

using bf16x8 = __attribute__((ext_vector_type(8))) short;
using f32x4  = __attribute__((ext_vector_type(4))) float;

__device__ __forceinline__ unsigned short f2bf(float f) {
    union { float f; uint32_t u; } x; x.f = f;
    uint32_t u = x.u;
    uint32_t r = (u + 0x7fffu + ((u >> 16) & 1u)) >> 16;
    return (unsigned short)r;
}
__device__ __forceinline__ float bf2f(unsigned short h) {
    union { uint32_t u; float f; } x; x.u = ((uint32_t)h) << 16;
    return x.f;
}
__device__ __forceinline__ float sigm(float v) { return 1.0f / (1.0f + expf(-v)); }
__device__ __forceinline__ float silu(float v) { return v / (1.0f + expf(-v)); }

__device__ __forceinline__ void gload_lds16(const void* g, void* l) {
    __builtin_amdgcn_global_load_lds(
        (__attribute__((address_space(1))) void*)(void*)g,
        (__attribute__((address_space(3))) void*)l, 16, 0, 0);
}

// ---------------- fused weight prep: transposes to bf16 [N][K] ----------------
// jobs (flat block id):
//   [0,4096)      in_proj  (K=1024,N=4096) -> inT
//   [4096,8192)   A_proj   (K=2048,N=2048) -> W2 rows 0..2047
//   [8192,10240)  out_proj (K=2048,N=1024) -> outT
//   [10240,10304) B_proj   (K=2048,N=16)   -> W2 rows 2048..2063
//   [10304,10368) C_proj   (K=2048,N=16)   -> W2 rows 2064..2079
__global__ __launch_bounds__(256)
void prep_weights(const float* __restrict__ in_proj, const float* __restrict__ A_proj,
                  const float* __restrict__ B_proj, const float* __restrict__ C_proj,
                  const float* __restrict__ out_proj,
                  unsigned short* __restrict__ inT, unsigned short* __restrict__ W2,
                  unsigned short* __restrict__ outT) {
    int bid = blockIdx.x;
    int tid = threadIdx.x;
    if (bid >= 10240) {        // B/C_proj: 16-wide transpose
        int l = bid - 10240;
        const float* src = (l < 64) ? B_proj : C_proj;
        int rowoff = (l < 64) ? 2048 : 2064;
        int k0 = (l & 63) * 32;
        int r = tid >> 4, c = tid & 15;     // r 0..15, c 0..15
#pragma unroll
        for (int rr = 0; rr < 32; rr += 16) {
            float v = src[(size_t)(k0 + r + rr) * 16 + c];
            W2[(size_t)(rowoff + c) * 2048 + (k0 + r + rr)] = f2bf(v);
        }
        return;
    }
    const float* src; unsigned short* dst; int K, N, l;
    if (bid < 4096)      { src = in_proj;  dst = inT;  K = 1024; N = 4096; l = bid; }
    else if (bid < 8192) { src = A_proj;   dst = W2;   K = 2048; N = 2048; l = bid - 4096; }
    else                 { src = out_proj; dst = outT; K = 2048; N = 1024; l = bid - 8192; }
    int ntiles = N >> 5;
    int n0 = (l % ntiles) * 32, k0 = (l / ntiles) * 32;
    __shared__ float tile[32][33];
    int tx = tid & 31, ty = tid >> 5;   // ty 0..7
#pragma unroll
    for (int i = 0; i < 32; i += 8)
        tile[ty + i][tx] = src[(size_t)(k0 + ty + i) * N + (n0 + tx)];
    __syncthreads();
    int sx = (tid & 15) * 2;   // k offset, even
    int sy = tid >> 4;         // n 0..15
#pragma unroll
    for (int i = 0; i < 32; i += 16) {
        int n = sy + i;
        float v0 = tile[sx][n], v1 = tile[sx + 1][n];
        size_t o = (size_t)(n0 + n) * K + (k0 + sx);
        *(ushort2*)&dst[o] = make_ushort2(f2bf(v0), f2bf(v1));
    }
}

// ---------------- RMSNorm -> single bf16 ----------------
__global__ __launch_bounds__(256)
void rmsnorm_bf(const float* __restrict__ x, const float* __restrict__ w,
                unsigned short* __restrict__ xh) {
    int row = blockIdx.x;            // 0..4095
    int tid = threadIdx.x;
    const float4* xr = (const float4*)(x + (size_t)row * H_);
    float4 v = xr[tid];
    float ss = v.x * v.x + v.y * v.y + v.z * v.z + v.w * v.w;
#pragma unroll
    for (int o = 32; o > 0; o >>= 1) ss += __shfl_down(ss, o, 64);
    __shared__ float red[4];
    int lane = tid & 63, wv = tid >> 6;
    if (lane == 0) red[wv] = ss;
    __syncthreads();
    float tot = red[0] + red[1] + red[2] + red[3];
    float rstd = rsqrtf(tot / (float)H_ + 1e-6f);
    const float4* wr = (const float4*)w;
    float4 w4 = wr[tid];
    size_t o = (size_t)row * H_ + tid * 4;
    *(ushort4*)&xh[o] = make_ushort4(f2bf(v.x * rstd * w4.x), f2bf(v.y * rstd * w4.y),
                                     f2bf(v.z * rstd * w4.z), f2bf(v.w * rstd * w4.w));
}

// ---------------- single-bf16 GEMM: C = A @ B^T, TM x 128 tile ----------------
// Fragment-order LDS: each 16x32 subtile stored so (row r, k-granule g) sits at
// byte (g*16+r)*16 -> every frag ds_read_b128 is base+lane*16 (linear, 0-conflict).
// Achieved by permuting per-lane GLOBAL source (linear global_load_lds dest).
// 3-buffer pipeline, counted vmcnt.
// EPI 0: xz -> silu; col<2048: x_in bf16, else silu_z bf16
// EPI 1: col<2048: a_mod=sigm(acc+aux[col]) fp16; 2048..2063: Bin fp32; 2064..2079: Cin
// EPI 2: out = acc + res[row*1024+col]  (fp32)
template <int EPI, int TM>
__global__ __launch_bounds__(256)
void gemm_bf(const unsigned short* __restrict__ Aa, const unsigned short* __restrict__ Bw,
             int K,
             float* __restrict__ out0,
             unsigned short* __restrict__ oh, unsigned short* __restrict__ oz,
             const float* __restrict__ aux,
             __half* __restrict__ oha, float* __restrict__ obin, float* __restrict__ ocin) {
    constexpr int UA    = TM / 16;        // A chunks (16 rows each)
    constexpr int UNITS = UA + 8;         // + 8 B chunks (128 cols)
    constexpr int SPW   = UNITS / 4;      // stage instrs per wave
    constexpr int WM    = TM / 32;        // m-frags per wave
    __shared__ unsigned short sm[3][UNITS * 512];
    const int tid  = threadIdx.x;
    const int lane = tid & 63;
    const int wid  = tid >> 6;
    const int wm   = wid >> 1, wn = wid & 1;
    const int bm   = blockIdx.y * TM;
    const int bn   = blockIdx.x * 128;

    // staging: unit u covers 16 rows x 32 k; lane s loads (row s&15, granule s>>4)
    const unsigned short* b0 = Aa + (size_t)bm * K;
    const unsigned short* b1 = Bw + (size_t)bn * K;
    const unsigned short* gp[SPW];
    int lofs[SPW];
#pragma unroll
    for (int j = 0; j < SPW; ++j) {
        int u = wid * SPW + j;
        const unsigned short* base = (u < UA) ? b0 : b1;
        int chunk = (u < UA) ? u : (u - UA);
        gp[j] = base + (size_t)(chunk * 16 + (lane & 15)) * K + (lane >> 4) * 8;
        lofs[j] = u * 512;
    }

    const int nk = K >> 5;
#pragma unroll
    for (int j = 0; j < SPW; ++j) gload_lds16(gp[j], &sm[0][lofs[j]]);
#pragma unroll
    for (int j = 0; j < SPW; ++j) gload_lds16(gp[j] + 32, &sm[1][lofs[j]]);

    f32x4 acc[WM][4] = {};
    int bsel = 0;
    for (int kt = 0; kt < nk; ++kt) {
        if (kt + 1 < nk) {
            if constexpr (SPW == 4) asm volatile("s_waitcnt vmcnt(4)" ::: "memory");
            else                    asm volatile("s_waitcnt vmcnt(3)" ::: "memory");
        } else {
            asm volatile("s_waitcnt vmcnt(0)" ::: "memory");
        }
        __builtin_amdgcn_s_barrier();
        __builtin_amdgcn_sched_barrier(0);
        if (kt + 2 < nk) {      // stage tile kt+2 into buffer of tile kt-1
            int nb = bsel + 2; if (nb >= 3) nb -= 3;
#pragma unroll
            for (int j = 0; j < SPW; ++j)
                gload_lds16(gp[j] + (kt + 2) * 32, &sm[nb][lofs[j]]);
        }
        const unsigned short* sb = sm[bsel];
        bf16x8 af[WM], bf8[4];
#pragma unroll
        for (int m = 0; m < WM; ++m)
            af[m] = *(const bf16x8*)&sb[(wm * WM + m) * 512 + lane * 8];
#pragma unroll
        for (int n = 0; n < 4; ++n)
            bf8[n] = *(const bf16x8*)&sb[(UA + wn * 4 + n) * 512 + lane * 8];
#pragma unroll
        for (int m = 0; m < WM; ++m)
#pragma unroll
            for (int n = 0; n < 4; ++n)
                acc[m][n] = __builtin_amdgcn_mfma_f32_16x16x32_bf16(af[m], bf8[n], acc[m][n], 0, 0, 0);
        bsel += 1; if (bsel == 3) bsel = 0;
    }

    // epilogue: C/D layout col=lane&15, row=(lane>>4)*4+reg  [m89-verified]
#pragma unroll
    for (int m = 0; m < WM; ++m)
#pragma unroll
        for (int n = 0; n < 4; ++n) {
            int col  = bn + wn * 64 + n * 16 + (lane & 15);
            int row0 = bm + wm * (WM * 16) + m * 16 + ((lane >> 4) << 2);
#pragma unroll
            for (int r = 0; r < 4; ++r) {
                int row = row0 + r;
                float v = acc[m][n][r];
                if (EPI == 0) {
                    float s = silu(v);
                    if (col < DIN_) oh[(size_t)row * DIN_ + col] = f2bf(s);
                    else            oz[(size_t)row * DIN_ + (col - DIN_)] = f2bf(s);
                } else if (EPI == 1) {
                    if (col < 2048)      oha[(size_t)row * DIN_ + col] = __float2half(sigm(v + aux[col]));
                    else if (col < 2064) obin[(size_t)row * 16 + (col - 2048)] = v;
                    else if (col < 2080) ocin[(size_t)row * 16 + (col - 2064)] = v;
                } else {
                    out0[(size_t)row * H_ + col] = v + aux[(size_t)row * H_ + col];
                }
            }
        }
}

// ---------------- chunked parallel scan ----------------
__global__ __launch_bounds__(256)
void scan_phase1(const __half* __restrict__ amod, const unsigned short* __restrict__ xh,
                 const float* __restrict__ Bin, const float* __restrict__ Abase,
                 float* __restrict__ P, float* __restrict__ S) {
    int d = blockIdx.x * 256 + threadIdx.x;   // 0..2047
    int c = blockIdx.y;
    int b = blockIdx.z;
    float ab[16];
#pragma unroll
    for (int n = 0; n < 16; ++n) ab[n] = sigm(Abase[n]);
    float p[16], s[16];
#pragma unroll
    for (int n = 0; n < 16; ++n) { p[n] = 1.0f; s[n] = 0.0f; }
    int t0 = c * LCHUNK;
    for (int tt = 0; tt < LCHUNK; ++tt) {
        size_t mrow = (size_t)(b * T_ + t0 + tt);
        float a = __half2float(amod[mrow * DIN_ + d]);
        float x = bf2f(xh[mrow * DIN_ + d]);
        const float4* bt4 = (const float4*)(Bin + mrow * 16);
        float4 q0 = bt4[0], q1 = bt4[1], q2 = bt4[2], q3 = bt4[3];
        float bt[16];
        bt[0]=q0.x; bt[1]=q0.y; bt[2]=q0.z; bt[3]=q0.w;
        bt[4]=q1.x; bt[5]=q1.y; bt[6]=q1.z; bt[7]=q1.w;
        bt[8]=q2.x; bt[9]=q2.y; bt[10]=q2.z; bt[11]=q2.w;
        bt[12]=q3.x; bt[13]=q3.y; bt[14]=q3.z; bt[15]=q3.w;
#pragma unroll
        for (int n = 0; n < 16; ++n) {
            float dk = a * ab[n];
            p[n] *= dk;
            s[n] = fmaf(dk, s[n], bt[n] * x);
        }
    }
    size_t base = ((size_t)(b * NCHUNK + c) << 15) + (size_t)d * 16;
    float4* P4 = (float4*)(P + base);
    float4* S4 = (float4*)(S + base);
#pragma unroll
    for (int j = 0; j < 4; ++j) {
        P4[j] = make_float4(p[4*j], p[4*j+1], p[4*j+2], p[4*j+3]);
        S4[j] = make_float4(s[4*j], s[4*j+1], s[4*j+2], s[4*j+3]);
    }
}

__global__ __launch_bounds__(256)
void scan_phase2(const float* __restrict__ P, const float* __restrict__ S,
                 float* __restrict__ H0) {
    int idx = blockIdx.x * 256 + threadIdx.x;   // 0..65535
    int b = idx >> 15;
    int dn = idx & 32767;
    float g = 0.f;
    for (int c = 0; c < NCHUNK; ++c) {
        size_t base = ((size_t)(b * NCHUNK + c) << 15) + dn;
        H0[base] = g;
        g = fmaf(P[base], g, S[base]);
    }
}

__global__ __launch_bounds__(256)
void scan_phase3(const __half* __restrict__ amod, const unsigned short* __restrict__ xh,
                 const float* __restrict__ Bin, const float* __restrict__ Cin,
                 const float* __restrict__ Abase, const float* __restrict__ H0,
                 const float* __restrict__ Dp, const unsigned short* __restrict__ szh,
                 unsigned short* __restrict__ yh) {
    int d = blockIdx.x * 256 + threadIdx.x;
    int c = blockIdx.y;
    int b = blockIdx.z;
    float ab[16];
#pragma unroll
    for (int n = 0; n < 16; ++n) ab[n] = sigm(Abase[n]);
    float h[16];
    size_t hbase = ((size_t)(b * NCHUNK + c) << 15) + (size_t)d * 16;
    const float4* H4 = (const float4*)(H0 + hbase);
#pragma unroll
    for (int j = 0; j < 4; ++j) {
        float4 t4 = H4[j];
        h[j*4] = t4.x; h[j*4+1] = t4.y; h[j*4+2] = t4.z; h[j*4+3] = t4.w;
    }
    float Dd = Dp[d];
    int t0 = c * LCHUNK;
    for (int tt = 0; tt < LCHUNK; ++tt) {
        size_t mrow = (size_t)(b * T_ + t0 + tt);
        float a = __half2float(amod[mrow * DIN_ + d]);
        float x = bf2f(xh[mrow * DIN_ + d]);
        const float4* bt4 = (const float4*)(Bin + mrow * 16);
        const float4* ct4 = (const float4*)(Cin + mrow * 16);
        float4 q0 = bt4[0], q1 = bt4[1], q2 = bt4[2], q3 = bt4[3];
        float4 r0 = ct4[0], r1 = ct4[1], r2 = ct4[2], r3 = ct4[3];
        float bt[16], ct[16];
        bt[0]=q0.x; bt[1]=q0.y; bt[2]=q0.z; bt[3]=q0.w;
        bt[4]=q1.x; bt[5]=q1.y; bt[6]=q1.z; bt[7]=q1.w;
        bt[8]=q2.x; bt[9]=q2.y; bt[10]=q2.z; bt[11]=q2.w;
        bt[12]=q3.x; bt[13]=q3.y; bt[14]=q3.z; bt[15]=q3.w;
        ct[0]=r0.x; ct[1]=r0.y; ct[2]=r0.z; ct[3]=r0.w;
        ct[4]=r1.x; ct[5]=r1.y; ct[6]=r1.z; ct[7]=r1.w;
        ct[8]=r2.x; ct[9]=r2.y; ct[10]=r2.z; ct[11]=r2.w;
        ct[12]=r3.x; ct[13]=r3.y; ct[14]=r3.z; ct[15]=r3.w;
        float y = 0.f;
#pragma unroll
        for (int n = 0; n < 16; ++n) {
            float dk = a * ab[n];
            h[n] = fmaf(dk, h[n], bt[n] * x);
            y = fmaf(h[n], ct[n], y);
        }
        float val = (y + Dd * x) * bf2f(szh[mrow * DIN_ + d]);
        yh[mrow * DIN_ + d] = f2bf(val);
    }
}

// ---------------- launch ----------------
extern "C" void kernel_launch(void* const* d_in, const int* in_sizes, int n_in,
                              void* d_out, int out_size, void* d_ws, size_t ws_size,
                              hipStream_t stream) {
    const float* x          = (const float*)d_in[0];
    const float* norm_w     = (const float*)d_in[1];
    const float* in_proj_w  = (const float*)d_in[2];
    const float* A_proj_w   = (const float*)d_in[3];
    const float* A_proj_b   = (const float*)d_in[4];
    const float* A_base     = (const float*)d_in[5];
    const float* B_proj_w   = (const float*)d_in[6];
    const float* C_proj_w   = (const float*)d_in[7];
    const float* Dp         = (const float*)d_in[8];
    const float* out_proj_w = (const float*)d_in[9];
    float* out = (float*)d_out;

    char* ws = (char*)d_ws;
    size_t off = 0;
    auto alloc = [&](size_t bytes) -> char* {
        char* p = ws + off;
        off += (bytes + 255) & ~(size_t)255;
        return p;
    };
    unsigned short* inT  = (unsigned short*)alloc((size_t)4096 * 1024 * 2);
    unsigned short* W2   = (unsigned short*)alloc((size_t)2176 * 2048 * 2);  // A|B|C + pad
    unsigned short* outT = (unsigned short*)alloc((size_t)1024 * 2048 * 2);
    unsigned short* xnh  = (unsigned short*)alloc((size_t)M_ * H_ * 2);
    unsigned short* xinh = (unsigned short*)alloc((size_t)M_ * DIN_ * 2);
    unsigned short* szh  = (unsigned short*)alloc((size_t)M_ * DIN_ * 2);
    __half* amod  = (__half*)alloc((size_t)M_ * DIN_ * 2);
    float* Bin    = (float*)alloc((size_t)M_ * 16 * 4);
    float* Cin    = (float*)alloc((size_t)M_ * 16 * 4);
    float* Pw     = (float*)alloc((size_t)B_ * NCHUNK * DIN_ * NS_ * 4);
    float* Sw     = (float*)alloc((size_t)B_ * NCHUNK * DIN_ * NS_ * 4);
    float* H0w    = (float*)alloc((size_t)B_ * NCHUNK * DIN_ * NS_ * 4);
    unsigned short* yh = (unsigned short*)alloc((size_t)M_ * DIN_ * 2);
    (void)ws_size;

    // fused weight prep (all transposes in one launch)
    prep_weights<<<10368, 256, 0, stream>>>(in_proj_w, A_proj_w, B_proj_w, C_proj_w,
                                            out_proj_w, inT, W2, outT);

    rmsnorm_bf<<<M_, 256, 0, stream>>>(x, norm_w, xnh);

    // xz = xn @ in_proj  (M=4096, N=4096, K=1024) -> x_in bf16 + silu_z bf16
    gemm_bf<0, 128><<<dim3(4096 / 128, M_ / 128), 256, 0, stream>>>(
        xnh, inT, 1024, nullptr, xinh, szh, nullptr, nullptr, nullptr, nullptr);

    // [a_mod | B_in | C_in] = x_in @ [A|B|C]  (N=2080 in 17 tiles, K=2048)
    gemm_bf<1, 128><<<dim3(17, M_ / 128), 256, 0, stream>>>(
        xinh, W2, 2048, nullptr, nullptr, nullptr, A_proj_b, amod, Bin, Cin);

    // chunked scan
    scan_phase1<<<dim3(DIN_ / 256, NCHUNK, B_), 256, 0, stream>>>(amod, xinh, Bin, A_base, Pw, Sw);
    scan_phase2<<<(B_ * DIN_ * NS_) / 256, 256, 0, stream>>>(Pw, Sw, H0w);
    scan_phase3<<<dim3(DIN_ / 256, NCHUNK, B_), 256, 0, stream>>>(
        amod, xinh, Bin, Cin, A_base, H0w, Dp, szh, yh);

    // out = residual + y @ out_proj  (N=1024, K=2048), 64x128 tiles -> 512 blocks
    gemm_bf<2, 64><<<dim3(1024 / 128, M_ / 64), 256, 0, stream>>>(
        yh, outT, 2048, out, nullptr, nullptr, x, nullptr, nullptr, nullptr);
}

// Round 5
// 248.492 us; speedup vs baseline: 2.0368x; 1.2529x over previous
//
#include <hip/hip_runtime.h>
#include <hip/hip_fp16.h>
#include <cstdint>

#define B_    2
#define T_    2048
#define H_    1024
#define DIN_  2048
#define NS_   16
#define M_    (B_*T_)     // 4096
#define NCHUNK 32
#define LCHUNK 64         // T_/NCHUNK

using bf16x8 = __attribute__((ext_vector_type(8))) short;
using f32x4  = __attribute__((ext_vector_type(4))) float;

__device__ __forceinline__ unsigned short f2bf(float f) {
    union { float f; uint32_t u; } x; x.f = f;
    uint32_t u = x.u;
    uint32_t r = (u + 0x7fffu + ((u >> 16) & 1u)) >> 16;
    return (unsigned short)r;
}
__device__ __forceinline__ float bf2f(unsigned short h) {
    union { uint32_t u; float f; } x; x.u = ((uint32_t)h) << 16;
    return x.f;
}
__device__ __forceinline__ float sigm(float v) { return 1.0f / (1.0f + expf(-v)); }
__device__ __forceinline__ float silu(float v) { return v / (1.0f + expf(-v)); }

__device__ __forceinline__ void gload_lds16(const void* g, void* l) {
    __builtin_amdgcn_global_load_lds(
        (__attribute__((address_space(1))) void*)(void*)g,
        (__attribute__((address_space(3))) void*)l, 16, 0, 0);
}

// ---------------- fused weight prep: transposes to bf16 [N][K] ----------------
__global__ __launch_bounds__(256)
void prep_weights(const float* __restrict__ in_proj, const float* __restrict__ A_proj,
                  const float* __restrict__ B_proj, const float* __restrict__ C_proj,
                  const float* __restrict__ out_proj,
                  unsigned short* __restrict__ inT, unsigned short* __restrict__ W2,
                  unsigned short* __restrict__ outT) {
    int bid = blockIdx.x;
    int tid = threadIdx.x;
    if (bid >= 10240) {        // B/C_proj: 16-wide transpose
        int l = bid - 10240;
        const float* src = (l < 64) ? B_proj : C_proj;
        int rowoff = (l < 64) ? 2048 : 2064;
        int k0 = (l & 63) * 32;
        int r = tid >> 4, c = tid & 15;     // r 0..15, c 0..15
#pragma unroll
        for (int rr = 0; rr < 32; rr += 16) {
            float v = src[(size_t)(k0 + r + rr) * 16 + c];
            W2[(size_t)(rowoff + c) * 2048 + (k0 + r + rr)] = f2bf(v);
        }
        return;
    }
    const float* src; unsigned short* dst; int K, N, l;
    if (bid < 4096)      { src = in_proj;  dst = inT;  K = 1024; N = 4096; l = bid; }
    else if (bid < 8192) { src = A_proj;   dst = W2;   K = 2048; N = 2048; l = bid - 4096; }
    else                 { src = out_proj; dst = outT; K = 2048; N = 1024; l = bid - 8192; }
    int ntiles = N >> 5;
    int n0 = (l % ntiles) * 32, k0 = (l / ntiles) * 32;
    __shared__ float tile[32][33];
    int tx = tid & 31, ty = tid >> 5;   // ty 0..7
#pragma unroll
    for (int i = 0; i < 32; i += 8)
        tile[ty + i][tx] = src[(size_t)(k0 + ty + i) * N + (n0 + tx)];
    __syncthreads();
    int sx = (tid & 15) * 2;   // k offset, even
    int sy = tid >> 4;         // n 0..15
#pragma unroll
    for (int i = 0; i < 32; i += 16) {
        int n = sy + i;
        float v0 = tile[sx][n], v1 = tile[sx + 1][n];
        size_t o = (size_t)(n0 + n) * K + (k0 + sx);
        *(ushort2*)&dst[o] = make_ushort2(f2bf(v0), f2bf(v1));
    }
}

// ---------------- RMSNorm -> single bf16 ----------------
__global__ __launch_bounds__(256)
void rmsnorm_bf(const float* __restrict__ x, const float* __restrict__ w,
                unsigned short* __restrict__ xh) {
    int row = blockIdx.x;            // 0..4095
    int tid = threadIdx.x;
    const float4* xr = (const float4*)(x + (size_t)row * H_);
    float4 v = xr[tid];
    float ss = v.x * v.x + v.y * v.y + v.z * v.z + v.w * v.w;
#pragma unroll
    for (int o = 32; o > 0; o >>= 1) ss += __shfl_down(ss, o, 64);
    __shared__ float red[4];
    int lane = tid & 63, wv = tid >> 6;
    if (lane == 0) red[wv] = ss;
    __syncthreads();
    float tot = red[0] + red[1] + red[2] + red[3];
    float rstd = rsqrtf(tot / (float)H_ + 1e-6f);
    const float4* wr = (const float4*)w;
    float4 w4 = wr[tid];
    size_t o = (size_t)row * H_ + tid * 4;
    *(ushort4*)&xh[o] = make_ushort4(f2bf(v.x * rstd * w4.x), f2bf(v.y * rstd * w4.y),
                                     f2bf(v.z * rstd * w4.z), f2bf(v.w * rstd * w4.w));
}

// ---------------- single-bf16 GEMM: C = A @ B^T, TM x 128 tile ----------------
// LDS unit = 16 rows x 64B, row-major, bank-group XOR swizzle:
//   slot (r,g) at byte r*64 + (g ^ ((r>>1)&3))*16
// -> frag ds_read (lane: r=lane&15, g=lane>>4) hits all 8 bank-groups, 2-way (free).
// Staging keeps 4-contiguous-lanes-per-row 64B coalescing (granule perm within row).
// 3-buffer pipeline, counted vmcnt. XCD-chunked block swizzle (T1).
// EPI 0: xz -> silu; col<2048: x_in bf16, else silu_z bf16
// EPI 1: col<2048: a_mod=sigm(acc+aux[col]) fp16; 2048..2063: Bin fp32; 2064..2079: Cin
// EPI 2: out = acc + res[row*1024+col]  (fp32)
template <int EPI, int TM>
__global__ __launch_bounds__(256)
void gemm_bf(const unsigned short* __restrict__ Aa, const unsigned short* __restrict__ Bw,
             int K,
             float* __restrict__ out0,
             unsigned short* __restrict__ oh, unsigned short* __restrict__ oz,
             const float* __restrict__ aux,
             __half* __restrict__ oha, float* __restrict__ obin, float* __restrict__ ocin) {
    constexpr int UA    = TM / 16;        // A chunks (16 rows each)
    constexpr int UNITS = UA + 8;         // + 8 B chunks (128 cols)
    constexpr int SPW   = UNITS / 4;      // stage instrs per wave
    constexpr int WM    = TM / 32;        // m-frags per wave
    __shared__ unsigned short sm[3][UNITS * 512];
    const int tid  = threadIdx.x;
    const int lane = tid & 63;
    const int wid  = tid >> 6;
    const int wm   = wid >> 1, wn = wid & 1;

    // XCD-chunked bijective block swizzle (grid sizes are multiples of 8)
    const int gx   = gridDim.x;
    const int nwg  = gx * gridDim.y;
    const int orig = blockIdx.y * gx + blockIdx.x;
    const int qq   = nwg >> 3;
    const int lid  = (orig & 7) * qq + (orig >> 3);
    const int bm   = (lid / gx) * TM;
    const int bn   = (lid % gx) * 128;

    // staging: unit u = 16 rows x 32k; lane s -> row s>>2, slot s&3,
    // source granule (s&3) ^ ((s>>3)&3)  [within-row 64B permutation]
    const unsigned short* b0 = Aa + (size_t)bm * K;
    const unsigned short* b1 = Bw + (size_t)bn * K;
    const int srow  = lane >> 2;
    const int sgran = (lane & 3) ^ ((lane >> 3) & 3);
    const unsigned short* gp[SPW];
    int lofs[SPW];
#pragma unroll
    for (int j = 0; j < SPW; ++j) {
        int u = wid * SPW + j;
        const unsigned short* base = (u < UA) ? b0 : b1;
        int chunk = (u < UA) ? u : (u - UA);
        gp[j] = base + (size_t)(chunk * 16 + srow) * K + sgran * 8;
        lofs[j] = u * 512;
    }

    const int nk = K >> 5;
#pragma unroll
    for (int j = 0; j < SPW; ++j) gload_lds16(gp[j], &sm[0][lofs[j]]);
#pragma unroll
    for (int j = 0; j < SPW; ++j) gload_lds16(gp[j] + 32, &sm[1][lofs[j]]);

    // frag read offset (ushorts): row (lane&15)*32, swizzled granule
    const int fro = (lane & 15) * 32 + (((lane >> 4) ^ ((lane >> 1) & 3)) * 8);

    f32x4 acc[WM][4] = {};
    int bsel = 0;
    for (int kt = 0; kt < nk; ++kt) {
        if (kt + 1 < nk) {
            if constexpr (SPW == 4) asm volatile("s_waitcnt vmcnt(4)" ::: "memory");
            else                    asm volatile("s_waitcnt vmcnt(3)" ::: "memory");
        } else {
            asm volatile("s_waitcnt vmcnt(0)" ::: "memory");
        }
        __builtin_amdgcn_s_barrier();
        __builtin_amdgcn_sched_barrier(0);
        if (kt + 2 < nk) {      // stage tile kt+2 into buffer of tile kt-1
            int nb = bsel + 2; if (nb >= 3) nb -= 3;
#pragma unroll
            for (int j = 0; j < SPW; ++j)
                gload_lds16(gp[j] + (kt + 2) * 32, &sm[nb][lofs[j]]);
        }
        const unsigned short* sb = sm[bsel];
        bf16x8 af[WM], bf8[4];
#pragma unroll
        for (int m = 0; m < WM; ++m)
            af[m] = *(const bf16x8*)&sb[(wm * WM + m) * 512 + fro];
#pragma unroll
        for (int n = 0; n < 4; ++n)
            bf8[n] = *(const bf16x8*)&sb[(UA + wn * 4 + n) * 512 + fro];
#pragma unroll
        for (int m = 0; m < WM; ++m)
#pragma unroll
            for (int n = 0; n < 4; ++n)
                acc[m][n] = __builtin_amdgcn_mfma_f32_16x16x32_bf16(af[m], bf8[n], acc[m][n], 0, 0, 0);
        bsel += 1; if (bsel == 3) bsel = 0;
    }

    // epilogue: C/D layout col=lane&15, row=(lane>>4)*4+reg  [m89-verified]
#pragma unroll
    for (int m = 0; m < WM; ++m)
#pragma unroll
        for (int n = 0; n < 4; ++n) {
            int col  = bn + wn * 64 + n * 16 + (lane & 15);
            int row0 = bm + wm * (WM * 16) + m * 16 + ((lane >> 4) << 2);
#pragma unroll
            for (int r = 0; r < 4; ++r) {
                int row = row0 + r;
                float v = acc[m][n][r];
                if (EPI == 0) {
                    float s = silu(v);
                    if (col < DIN_) oh[(size_t)row * DIN_ + col] = f2bf(s);
                    else            oz[(size_t)row * DIN_ + (col - DIN_)] = f2bf(s);
                } else if (EPI == 1) {
                    if (col < 2048)      oha[(size_t)row * DIN_ + col] = __float2half(sigm(v + aux[col]));
                    else if (col < 2064) obin[(size_t)row * 16 + (col - 2048)] = v;
                    else if (col < 2080) ocin[(size_t)row * 16 + (col - 2064)] = v;
                } else {
                    out0[(size_t)row * H_ + col] = v + aux[(size_t)row * H_ + col];
                }
            }
        }
}

// ---------------- chunked parallel scan ----------------
__global__ __launch_bounds__(256)
void scan_phase1(const __half* __restrict__ amod, const unsigned short* __restrict__ xh,
                 const float* __restrict__ Bin, const float* __restrict__ Abase,
                 float* __restrict__ P, float* __restrict__ S) {
    int d = blockIdx.x * 256 + threadIdx.x;   // 0..2047
    int c = blockIdx.y;
    int b = blockIdx.z;
    float ab[16];
#pragma unroll
    for (int n = 0; n < 16; ++n) ab[n] = sigm(Abase[n]);
    float p[16], s[16];
#pragma unroll
    for (int n = 0; n < 16; ++n) { p[n] = 1.0f; s[n] = 0.0f; }
    int t0 = c * LCHUNK;
    for (int tt = 0; tt < LCHUNK; ++tt) {
        size_t mrow = (size_t)(b * T_ + t0 + tt);
        float a = __half2float(amod[mrow * DIN_ + d]);
        float x = bf2f(xh[mrow * DIN_ + d]);
        const float4* bt4 = (const float4*)(Bin + mrow * 16);
        float4 q0 = bt4[0], q1 = bt4[1], q2 = bt4[2], q3 = bt4[3];
        float bt[16];
        bt[0]=q0.x; bt[1]=q0.y; bt[2]=q0.z; bt[3]=q0.w;
        bt[4]=q1.x; bt[5]=q1.y; bt[6]=q1.z; bt[7]=q1.w;
        bt[8]=q2.x; bt[9]=q2.y; bt[10]=q2.z; bt[11]=q2.w;
        bt[12]=q3.x; bt[13]=q3.y; bt[14]=q3.z; bt[15]=q3.w;
#pragma unroll
        for (int n = 0; n < 16; ++n) {
            float dk = a * ab[n];
            p[n] *= dk;
            s[n] = fmaf(dk, s[n], bt[n] * x);
        }
    }
    size_t base = ((size_t)(b * NCHUNK + c) << 15) + (size_t)d * 16;
    float4* P4 = (float4*)(P + base);
    float4* S4 = (float4*)(S + base);
#pragma unroll
    for (int j = 0; j < 4; ++j) {
        P4[j] = make_float4(p[4*j], p[4*j+1], p[4*j+2], p[4*j+3]);
        S4[j] = make_float4(s[4*j], s[4*j+1], s[4*j+2], s[4*j+3]);
    }
}

__global__ __launch_bounds__(256)
void scan_phase2(const float* __restrict__ P, const float* __restrict__ S,
                 float* __restrict__ H0) {
    int idx = blockIdx.x * 256 + threadIdx.x;   // 0..65535
    int b = idx >> 15;
    int dn = idx & 32767;
    float g = 0.f;
    for (int c = 0; c < NCHUNK; ++c) {
        size_t base = ((size_t)(b * NCHUNK + c) << 15) + dn;
        H0[base] = g;
        g = fmaf(P[base], g, S[base]);
    }
}

__global__ __launch_bounds__(256)
void scan_phase3(const __half* __restrict__ amod, const unsigned short* __restrict__ xh,
                 const float* __restrict__ Bin, const float* __restrict__ Cin,
                 const float* __restrict__ Abase, const float* __restrict__ H0,
                 const float* __restrict__ Dp, const unsigned short* __restrict__ szh,
                 unsigned short* __restrict__ yh) {
    int d = blockIdx.x * 256 + threadIdx.x;
    int c = blockIdx.y;
    int b = blockIdx.z;
    float ab[16];
#pragma unroll
    for (int n = 0; n < 16; ++n) ab[n] = sigm(Abase[n]);
    float h[16];
    size_t hbase = ((size_t)(b * NCHUNK + c) << 15) + (size_t)d * 16;
    const float4* H4 = (const float4*)(H0 + hbase);
#pragma unroll
    for (int j = 0; j < 4; ++j) {
        float4 t4 = H4[j];
        h[j*4] = t4.x; h[j*4+1] = t4.y; h[j*4+2] = t4.z; h[j*4+3] = t4.w;
    }
    float Dd = Dp[d];
    int t0 = c * LCHUNK;
    for (int tt = 0; tt < LCHUNK; ++tt) {
        size_t mrow = (size_t)(b * T_ + t0 + tt);
        float a = __half2float(amod[mrow * DIN_ + d]);
        float x = bf2f(xh[mrow * DIN_ + d]);
        const float4* bt4 = (const float4*)(Bin + mrow * 16);
        const float4* ct4 = (const float4*)(Cin + mrow * 16);
        float4 q0 = bt4[0], q1 = bt4[1], q2 = bt4[2], q3 = bt4[3];
        float4 r0 = ct4[0], r1 = ct4[1], r2 = ct4[2], r3 = ct4[3];
        float bt[16], ct[16];
        bt[0]=q0.x; bt[1]=q0.y; bt[2]=q0.z; bt[3]=q0.w;
        bt[4]=q1.x; bt[5]=q1.y; bt[6]=q1.z; bt[7]=q1.w;
        bt[8]=q2.x; bt[9]=q2.y; bt[10]=q2.z; bt[11]=q2.w;
        bt[12]=q3.x; bt[13]=q3.y; bt[14]=q3.z; bt[15]=q3.w;
        ct[0]=r0.x; ct[1]=r0.y; ct[2]=r0.z; ct[3]=r0.w;
        ct[4]=r1.x; ct[5]=r1.y; ct[6]=r1.z; ct[7]=r1.w;
        ct[8]=r2.x; ct[9]=r2.y; ct[10]=r2.z; ct[11]=r2.w;
        ct[12]=r3.x; ct[13]=r3.y; ct[14]=r3.z; ct[15]=r3.w;
        float y = 0.f;
#pragma unroll
        for (int n = 0; n < 16; ++n) {
            float dk = a * ab[n];
            h[n] = fmaf(dk, h[n], bt[n] * x);
            y = fmaf(h[n], ct[n], y);
        }
        float val = (y + Dd * x) * bf2f(szh[mrow * DIN_ + d]);
        yh[mrow * DIN_ + d] = f2bf(val);
    }
}

// ---------------- launch ----------------
extern "C" void kernel_launch(void* const* d_in, const int* in_sizes, int n_in,
                              void* d_out, int out_size, void* d_ws, size_t ws_size,
                              hipStream_t stream) {
    const float* x          = (const float*)d_in[0];
    const float* norm_w     = (const float*)d_in[1];
    const float* in_proj_w  = (const float*)d_in[2];
    const float* A_proj_w   = (const float*)d_in[3];
    const float* A_proj_b   = (const float*)d_in[4];
    const float* A_base     = (const float*)d_in[5];
    const float* B_proj_w   = (const float*)d_in[6];
    const float* C_proj_w   = (const float*)d_in[7];
    const float* Dp         = (const float*)d_in[8];
    const float* out_proj_w = (const float*)d_in[9];
    float* out = (float*)d_out;

    char* ws = (char*)d_ws;
    size_t off = 0;
    auto alloc = [&](size_t bytes) -> char* {
        char* p = ws + off;
        off += (bytes + 255) & ~(size_t)255;
        return p;
    };
    unsigned short* inT  = (unsigned short*)alloc((size_t)4096 * 1024 * 2);
    unsigned short* W2   = (unsigned short*)alloc((size_t)2176 * 2048 * 2);  // A|B|C + pad
    unsigned short* outT = (unsigned short*)alloc((size_t)1024 * 2048 * 2);
    unsigned short* xnh  = (unsigned short*)alloc((size_t)M_ * H_ * 2);
    unsigned short* xinh = (unsigned short*)alloc((size_t)M_ * DIN_ * 2);
    unsigned short* szh  = (unsigned short*)alloc((size_t)M_ * DIN_ * 2);
    __half* amod  = (__half*)alloc((size_t)M_ * DIN_ * 2);
    float* Bin    = (float*)alloc((size_t)M_ * 16 * 4);
    float* Cin    = (float*)alloc((size_t)M_ * 16 * 4);
    float* Pw     = (float*)alloc((size_t)B_ * NCHUNK * DIN_ * NS_ * 4);
    float* Sw     = (float*)alloc((size_t)B_ * NCHUNK * DIN_ * NS_ * 4);
    float* H0w    = (float*)alloc((size_t)B_ * NCHUNK * DIN_ * NS_ * 4);
    unsigned short* yh = (unsigned short*)alloc((size_t)M_ * DIN_ * 2);
    (void)ws_size;

    // fused weight prep (all transposes in one launch)
    prep_weights<<<10368, 256, 0, stream>>>(in_proj_w, A_proj_w, B_proj_w, C_proj_w,
                                            out_proj_w, inT, W2, outT);

    rmsnorm_bf<<<M_, 256, 0, stream>>>(x, norm_w, xnh);

    // xz = xn @ in_proj  (M=4096, N=4096, K=1024) -> x_in bf16 + silu_z bf16
    gemm_bf<0, 128><<<dim3(4096 / 128, M_ / 128), 256, 0, stream>>>(
        xnh, inT, 1024, nullptr, xinh, szh, nullptr, nullptr, nullptr, nullptr);

    // [a_mod | B_in | C_in] = x_in @ [A|B|C]  (N=2080 in 17 tiles, K=2048)
    gemm_bf<1, 128><<<dim3(17, M_ / 128), 256, 0, stream>>>(
        xinh, W2, 2048, nullptr, nullptr, nullptr, A_proj_b, amod, Bin, Cin);

    // chunked scan
    scan_phase1<<<dim3(DIN_ / 256, NCHUNK, B_), 256, 0, stream>>>(amod, xinh, Bin, A_base, Pw, Sw);
    scan_phase2<<<(B_ * DIN_ * NS_) / 256, 256, 0, stream>>>(Pw, Sw, H0w);
    scan_phase3<<<dim3(DIN_ / 256, NCHUNK, B_), 256, 0, stream>>>(
        amod, xinh, Bin, Cin, A_base, H0w, Dp, szh, yh);

    // out = residual + y @ out_proj  (N=1024, K=2048), 64x128 tiles -> 512 blocks
    gemm_bf<2, 64><<<dim3(1024 / 128, M_ / 64), 256, 0, stream>>>(
        yh, outT, 2048, out, nullptr, nullptr, x, nullptr, nullptr, nullptr);
}

// Round 6
// 238.489 us; speedup vs baseline: 2.1222x; 1.0419x over previous
//
#include <hip/hip_runtime.h>
#include <hip/hip_fp16.h>
#include <cstdint>

#define B_    2
#define T_    2048
#define H_    1024
#define DIN_  2048
#define NS_   16
#define M_    (B_*T_)     // 4096
#define NCHUNK 32
#define LCHUNK 64         // T_/NCHUNK

using bf16x8 = __attribute__((ext_vector_type(8))) short;
using f32x4  = __attribute__((ext_vector_type(4))) float;

__device__ __forceinline__ unsigned short f2bf(float f) {
    union { float f; uint32_t u; } x; x.f = f;
    uint32_t u = x.u;
    uint32_t r = (u + 0x7fffu + ((u >> 16) & 1u)) >> 16;
    return (unsigned short)r;
}
__device__ __forceinline__ float bf2f(unsigned short h) {
    union { uint32_t u; float f; } x; x.u = ((uint32_t)h) << 16;
    return x.f;
}
__device__ __forceinline__ float sigm(float v) { return 1.0f / (1.0f + expf(-v)); }
__device__ __forceinline__ float silu(float v) { return v / (1.0f + expf(-v)); }

__device__ __forceinline__ void gload_lds16(const void* g, void* l) {
    __builtin_amdgcn_global_load_lds(
        (__attribute__((address_space(1))) void*)(void*)g,
        (__attribute__((address_space(3))) void*)l, 16, 0, 0);
}

// ---------------- fused weight prep: transposes to bf16 [N][K] ----------------
__global__ __launch_bounds__(256)
void prep_weights(const float* __restrict__ in_proj, const float* __restrict__ A_proj,
                  const float* __restrict__ B_proj, const float* __restrict__ C_proj,
                  const float* __restrict__ out_proj,
                  unsigned short* __restrict__ inT, unsigned short* __restrict__ W2,
                  unsigned short* __restrict__ outT) {
    int bid = blockIdx.x;
    int tid = threadIdx.x;
    if (bid >= 10240) {        // B/C_proj: 16-wide transpose
        int l = bid - 10240;
        const float* src = (l < 64) ? B_proj : C_proj;
        int rowoff = (l < 64) ? 2048 : 2064;
        int k0 = (l & 63) * 32;
        int r = tid >> 4, c = tid & 15;     // r 0..15, c 0..15
#pragma unroll
        for (int rr = 0; rr < 32; rr += 16) {
            float v = src[(size_t)(k0 + r + rr) * 16 + c];
            W2[(size_t)(rowoff + c) * 2048 + (k0 + r + rr)] = f2bf(v);
        }
        return;
    }
    const float* src; unsigned short* dst; int K, N, l;
    if (bid < 4096)      { src = in_proj;  dst = inT;  K = 1024; N = 4096; l = bid; }
    else if (bid < 8192) { src = A_proj;   dst = W2;   K = 2048; N = 2048; l = bid - 4096; }
    else                 { src = out_proj; dst = outT; K = 2048; N = 1024; l = bid - 8192; }
    int ntiles = N >> 5;
    int n0 = (l % ntiles) * 32, k0 = (l / ntiles) * 32;
    __shared__ float tile[32][33];
    int tx = tid & 31, ty = tid >> 5;   // ty 0..7
#pragma unroll
    for (int i = 0; i < 32; i += 8)
        tile[ty + i][tx] = src[(size_t)(k0 + ty + i) * N + (n0 + tx)];
    __syncthreads();
    int sx = (tid & 15) * 2;   // k offset, even
    int sy = tid >> 4;         // n 0..15
#pragma unroll
    for (int i = 0; i < 32; i += 16) {
        int n = sy + i;
        float v0 = tile[sx][n], v1 = tile[sx + 1][n];
        size_t o = (size_t)(n0 + n) * K + (k0 + sx);
        *(ushort2*)&dst[o] = make_ushort2(f2bf(v0), f2bf(v1));
    }
}

// ---------------- RMSNorm -> single bf16 ----------------
__global__ __launch_bounds__(256)
void rmsnorm_bf(const float* __restrict__ x, const float* __restrict__ w,
                unsigned short* __restrict__ xh) {
    int row = blockIdx.x;            // 0..4095
    int tid = threadIdx.x;
    const float4* xr = (const float4*)(x + (size_t)row * H_);
    float4 v = xr[tid];
    float ss = v.x * v.x + v.y * v.y + v.z * v.z + v.w * v.w;
#pragma unroll
    for (int o = 32; o > 0; o >>= 1) ss += __shfl_down(ss, o, 64);
    __shared__ float red[4];
    int lane = tid & 63, wv = tid >> 6;
    if (lane == 0) red[wv] = ss;
    __syncthreads();
    float tot = red[0] + red[1] + red[2] + red[3];
    float rstd = rsqrtf(tot / (float)H_ + 1e-6f);
    const float4* wr = (const float4*)w;
    float4 w4 = wr[tid];
    size_t o = (size_t)row * H_ + tid * 4;
    *(ushort4*)&xh[o] = make_ushort4(f2bf(v.x * rstd * w4.x), f2bf(v.y * rstd * w4.y),
                                     f2bf(v.z * rstd * w4.z), f2bf(v.w * rstd * w4.w));
}

// ---------------- single-bf16 GEMM: C = A @ B^T, TM x 128 tile ----------------
// TM=256: 8 waves (2/SIMD, in-block stagger); TM=128/64: 4 waves.
// LDS unit = 16 rows x 64B, bank-group XOR swizzle: slot (r,g) at r*64 + (g^((r>>1)&3))*16
// -> frag ds_read hits all 8 bank-groups, 2-way (free). Staging keeps 64B/row coalescing.
// 3-buffer pipeline, counted vmcnt, T1 XCD swizzle, T5 setprio around MFMA.
// EPI 0: xz -> silu; col<2048: x_in bf16, else silu_z bf16
// EPI 1: col<2048: a_mod=sigm(acc+aux[col]) fp16; 2048..2063: Bin fp32; 2064..2079: Cin
// EPI 2: out = acc + res[row*1024+col]  (fp32)
template <int EPI, int TM>
__global__ __launch_bounds__((TM == 256) ? 512 : 256)
void gemm_bf(const unsigned short* __restrict__ Aa, const unsigned short* __restrict__ Bw,
             int K,
             float* __restrict__ out0,
             unsigned short* __restrict__ oh, unsigned short* __restrict__ oz,
             const float* __restrict__ aux,
             __half* __restrict__ oha, float* __restrict__ obin, float* __restrict__ ocin) {
    constexpr int WAVES = (TM == 256) ? 8 : 4;
    constexpr int UA    = TM / 16;            // A chunks (16 rows each)
    constexpr int UNITS = UA + 8;             // + 8 B chunks (128 cols)
    constexpr int SPW   = UNITS / WAVES;      // stage instrs per wave (3 or 4)
    constexpr int WM    = (TM * 2) / (WAVES * 16);  // m-frags per wave (4 or 2)
    static_assert(SPW * WAVES == UNITS, "stage split");
    __shared__ unsigned short sm[3][UNITS * 512];
    const int tid  = threadIdx.x;
    const int lane = tid & 63;
    const int wid  = tid >> 6;
    const int wm   = wid >> 1, wn = wid & 1;

    // XCD-chunked bijective block swizzle (grid sizes are multiples of 8)
    const int gx   = gridDim.x;
    const int nwg  = gx * gridDim.y;
    const int orig = blockIdx.y * gx + blockIdx.x;
    const int qq   = nwg >> 3;
    const int lid  = (orig & 7) * qq + (orig >> 3);
    const int bm   = (lid / gx) * TM;
    const int bn   = (lid % gx) * 128;

    // staging: unit u = 16 rows x 32k; lane s -> row s>>2, slot s&3,
    // source granule (s&3) ^ ((s>>3)&3)  [within-row 64B permutation]
    const unsigned short* b0 = Aa + (size_t)bm * K;
    const unsigned short* b1 = Bw + (size_t)bn * K;
    const int srow  = lane >> 2;
    const int sgran = (lane & 3) ^ ((lane >> 3) & 3);
    const unsigned short* gp[SPW];
    int lofs[SPW];
#pragma unroll
    for (int j = 0; j < SPW; ++j) {
        int u = wid * SPW + j;
        const unsigned short* base = (u < UA) ? b0 : b1;
        int chunk = (u < UA) ? u : (u - UA);
        gp[j] = base + (size_t)(chunk * 16 + srow) * K + sgran * 8;
        lofs[j] = u * 512;
    }

    const int nk = K >> 5;
#pragma unroll
    for (int j = 0; j < SPW; ++j) gload_lds16(gp[j], &sm[0][lofs[j]]);
#pragma unroll
    for (int j = 0; j < SPW; ++j) gload_lds16(gp[j] + 32, &sm[1][lofs[j]]);

    // frag read offset (ushorts): row (lane&15)*32, swizzled granule
    const int fro = (lane & 15) * 32 + (((lane >> 4) ^ ((lane >> 1) & 3)) * 8);

    f32x4 acc[WM][4] = {};
    int bsel = 0;
    for (int kt = 0; kt < nk; ++kt) {
        if (kt + 1 < nk) {
            if constexpr (SPW == 4) asm volatile("s_waitcnt vmcnt(4)" ::: "memory");
            else                    asm volatile("s_waitcnt vmcnt(3)" ::: "memory");
        } else {
            asm volatile("s_waitcnt vmcnt(0)" ::: "memory");
        }
        __builtin_amdgcn_s_barrier();
        __builtin_amdgcn_sched_barrier(0);
        if (kt + 2 < nk) {      // stage tile kt+2 into buffer of tile kt-1
            int nb = bsel + 2; if (nb >= 3) nb -= 3;
#pragma unroll
            for (int j = 0; j < SPW; ++j)
                gload_lds16(gp[j] + (kt + 2) * 32, &sm[nb][lofs[j]]);
        }
        const unsigned short* sb = sm[bsel];
        bf16x8 af[WM], bf8[4];
#pragma unroll
        for (int m = 0; m < WM; ++m)
            af[m] = *(const bf16x8*)&sb[(wm * WM + m) * 512 + fro];
#pragma unroll
        for (int n = 0; n < 4; ++n)
            bf8[n] = *(const bf16x8*)&sb[(UA + wn * 4 + n) * 512 + fro];
        __builtin_amdgcn_s_setprio(1);
#pragma unroll
        for (int m = 0; m < WM; ++m)
#pragma unroll
            for (int n = 0; n < 4; ++n)
                acc[m][n] = __builtin_amdgcn_mfma_f32_16x16x32_bf16(af[m], bf8[n], acc[m][n], 0, 0, 0);
        __builtin_amdgcn_s_setprio(0);
        bsel += 1; if (bsel == 3) bsel = 0;
    }

    // epilogue: C/D layout col=lane&15, row=(lane>>4)*4+reg  [m89-verified]
#pragma unroll
    for (int m = 0; m < WM; ++m)
#pragma unroll
        for (int n = 0; n < 4; ++n) {
            int col  = bn + wn * 64 + n * 16 + (lane & 15);
            int row0 = bm + wm * (WM * 16) + m * 16 + ((lane >> 4) << 2);
#pragma unroll
            for (int r = 0; r < 4; ++r) {
                int row = row0 + r;
                float v = acc[m][n][r];
                if (EPI == 0) {
                    float s = silu(v);
                    if (col < DIN_) oh[(size_t)row * DIN_ + col] = f2bf(s);
                    else            oz[(size_t)row * DIN_ + (col - DIN_)] = f2bf(s);
                } else if (EPI == 1) {
                    if (col < 2048)      oha[(size_t)row * DIN_ + col] = __float2half(sigm(v + aux[col]));
                    else if (col < 2064) obin[(size_t)row * 16 + (col - 2048)] = v;
                    else if (col < 2080) ocin[(size_t)row * 16 + (col - 2064)] = v;
                } else {
                    out0[(size_t)row * H_ + col] = v + aux[(size_t)row * H_ + col];
                }
            }
        }
}

// ---------------- chunked parallel scan ----------------
__global__ __launch_bounds__(256)
void scan_phase1(const __half* __restrict__ amod, const unsigned short* __restrict__ xh,
                 const float* __restrict__ Bin, const float* __restrict__ Abase,
                 float* __restrict__ P, float* __restrict__ S) {
    int d = blockIdx.x * 256 + threadIdx.x;   // 0..2047
    int c = blockIdx.y;
    int b = blockIdx.z;
    float ab[16];
#pragma unroll
    for (int n = 0; n < 16; ++n) ab[n] = sigm(Abase[n]);
    float p[16], s[16];
#pragma unroll
    for (int n = 0; n < 16; ++n) { p[n] = 1.0f; s[n] = 0.0f; }
    int t0 = c * LCHUNK;
    for (int tt = 0; tt < LCHUNK; ++tt) {
        size_t mrow = (size_t)(b * T_ + t0 + tt);
        float a = __half2float(amod[mrow * DIN_ + d]);
        float x = bf2f(xh[mrow * DIN_ + d]);
        const float4* bt4 = (const float4*)(Bin + mrow * 16);
        float4 q0 = bt4[0], q1 = bt4[1], q2 = bt4[2], q3 = bt4[3];
        float bt[16];
        bt[0]=q0.x; bt[1]=q0.y; bt[2]=q0.z; bt[3]=q0.w;
        bt[4]=q1.x; bt[5]=q1.y; bt[6]=q1.z; bt[7]=q1.w;
        bt[8]=q2.x; bt[9]=q2.y; bt[10]=q2.z; bt[11]=q2.w;
        bt[12]=q3.x; bt[13]=q3.y; bt[14]=q3.z; bt[15]=q3.w;
#pragma unroll
        for (int n = 0; n < 16; ++n) {
            float dk = a * ab[n];
            p[n] *= dk;
            s[n] = fmaf(dk, s[n], bt[n] * x);
        }
    }
    size_t base = ((size_t)(b * NCHUNK + c) << 15) + (size_t)d * 16;
    float4* P4 = (float4*)(P + base);
    float4* S4 = (float4*)(S + base);
#pragma unroll
    for (int j = 0; j < 4; ++j) {
        P4[j] = make_float4(p[4*j], p[4*j+1], p[4*j+2], p[4*j+3]);
        S4[j] = make_float4(s[4*j], s[4*j+1], s[4*j+2], s[4*j+3]);
    }
}

__global__ __launch_bounds__(256)
void scan_phase2(const float* __restrict__ P, const float* __restrict__ S,
                 float* __restrict__ H0) {
    int idx = blockIdx.x * 256 + threadIdx.x;   // 0..65535
    int b = idx >> 15;
    int dn = idx & 32767;
    float g = 0.f;
    for (int c = 0; c < NCHUNK; ++c) {
        size_t base = ((size_t)(b * NCHUNK + c) << 15) + dn;
        H0[base] = g;
        g = fmaf(P[base], g, S[base]);
    }
}

__global__ __launch_bounds__(256)
void scan_phase3(const __half* __restrict__ amod, const unsigned short* __restrict__ xh,
                 const float* __restrict__ Bin, const float* __restrict__ Cin,
                 const float* __restrict__ Abase, const float* __restrict__ H0,
                 const float* __restrict__ Dp, const unsigned short* __restrict__ szh,
                 unsigned short* __restrict__ yh) {
    int d = blockIdx.x * 256 + threadIdx.x;
    int c = blockIdx.y;
    int b = blockIdx.z;
    float ab[16];
#pragma unroll
    for (int n = 0; n < 16; ++n) ab[n] = sigm(Abase[n]);
    float h[16];
    size_t hbase = ((size_t)(b * NCHUNK + c) << 15) + (size_t)d * 16;
    const float4* H4 = (const float4*)(H0 + hbase);
#pragma unroll
    for (int j = 0; j < 4; ++j) {
        float4 t4 = H4[j];
        h[j*4] = t4.x; h[j*4+1] = t4.y; h[j*4+2] = t4.z; h[j*4+3] = t4.w;
    }
    float Dd = Dp[d];
    int t0 = c * LCHUNK;
    for (int tt = 0; tt < LCHUNK; ++tt) {
        size_t mrow = (size_t)(b * T_ + t0 + tt);
        float a = __half2float(amod[mrow * DIN_ + d]);
        float x = bf2f(xh[mrow * DIN_ + d]);
        const float4* bt4 = (const float4*)(Bin + mrow * 16);
        const float4* ct4 = (const float4*)(Cin + mrow * 16);
        float4 q0 = bt4[0], q1 = bt4[1], q2 = bt4[2], q3 = bt4[3];
        float4 r0 = ct4[0], r1 = ct4[1], r2 = ct4[2], r3 = ct4[3];
        float bt[16], ct[16];
        bt[0]=q0.x; bt[1]=q0.y; bt[2]=q0.z; bt[3]=q0.w;
        bt[4]=q1.x; bt[5]=q1.y; bt[6]=q1.z; bt[7]=q1.w;
        bt[8]=q2.x; bt[9]=q2.y; bt[10]=q2.z; bt[11]=q2.w;
        bt[12]=q3.x; bt[13]=q3.y; bt[14]=q3.z; bt[15]=q3.w;
        ct[0]=r0.x; ct[1]=r0.y; ct[2]=r0.z; ct[3]=r0.w;
        ct[4]=r1.x; ct[5]=r1.y; ct[6]=r1.z; ct[7]=r1.w;
        ct[8]=r2.x; ct[9]=r2.y; ct[10]=r2.z; ct[11]=r2.w;
        ct[12]=r3.x; ct[13]=r3.y; ct[14]=r3.z; ct[15]=r3.w;
        float y = 0.f;
#pragma unroll
        for (int n = 0; n < 16; ++n) {
            float dk = a * ab[n];
            h[n] = fmaf(dk, h[n], bt[n] * x);
            y = fmaf(h[n], ct[n], y);
        }
        float val = (y + Dd * x) * bf2f(szh[mrow * DIN_ + d]);
        yh[mrow * DIN_ + d] = f2bf(val);
    }
}

// ---------------- launch ----------------
extern "C" void kernel_launch(void* const* d_in, const int* in_sizes, int n_in,
                              void* d_out, int out_size, void* d_ws, size_t ws_size,
                              hipStream_t stream) {
    const float* x          = (const float*)d_in[0];
    const float* norm_w     = (const float*)d_in[1];
    const float* in_proj_w  = (const float*)d_in[2];
    const float* A_proj_w   = (const float*)d_in[3];
    const float* A_proj_b   = (const float*)d_in[4];
    const float* A_base     = (const float*)d_in[5];
    const float* B_proj_w   = (const float*)d_in[6];
    const float* C_proj_w   = (const float*)d_in[7];
    const float* Dp         = (const float*)d_in[8];
    const float* out_proj_w = (const float*)d_in[9];
    float* out = (float*)d_out;

    char* ws = (char*)d_ws;
    size_t off = 0;
    auto alloc = [&](size_t bytes) -> char* {
        char* p = ws + off;
        off += (bytes + 255) & ~(size_t)255;
        return p;
    };
    unsigned short* inT  = (unsigned short*)alloc((size_t)4096 * 1024 * 2);
    unsigned short* W2   = (unsigned short*)alloc((size_t)2176 * 2048 * 2);  // A|B|C + pad
    unsigned short* outT = (unsigned short*)alloc((size_t)1024 * 2048 * 2);
    unsigned short* xnh  = (unsigned short*)alloc((size_t)M_ * H_ * 2);
    unsigned short* xinh = (unsigned short*)alloc((size_t)M_ * DIN_ * 2);
    unsigned short* szh  = (unsigned short*)alloc((size_t)M_ * DIN_ * 2);
    __half* amod  = (__half*)alloc((size_t)M_ * DIN_ * 2);
    float* Bin    = (float*)alloc((size_t)M_ * 16 * 4);
    float* Cin    = (float*)alloc((size_t)M_ * 16 * 4);
    float* Pw     = (float*)alloc((size_t)B_ * NCHUNK * DIN_ * NS_ * 4);
    float* Sw     = (float*)alloc((size_t)B_ * NCHUNK * DIN_ * NS_ * 4);
    float* H0w    = (float*)alloc((size_t)B_ * NCHUNK * DIN_ * NS_ * 4);
    unsigned short* yh = (unsigned short*)alloc((size_t)M_ * DIN_ * 2);
    (void)ws_size;

    // fused weight prep (all transposes in one launch)
    prep_weights<<<10368, 256, 0, stream>>>(in_proj_w, A_proj_w, B_proj_w, C_proj_w,
                                            out_proj_w, inT, W2, outT);

    rmsnorm_bf<<<M_, 256, 0, stream>>>(x, norm_w, xnh);

    // xz = xn @ in_proj  (M=4096, N=4096, K=1024): 256x128 tiles, 8 waves -> 512 blocks
    gemm_bf<0, 256><<<dim3(4096 / 128, M_ / 256), 512, 0, stream>>>(
        xnh, inT, 1024, nullptr, xinh, szh, nullptr, nullptr, nullptr, nullptr);

    // [a_mod | B_in | C_in] = x_in @ [A|B|C]  (N=2080 in 17 col-tiles, K=2048) -> 272 blocks
    gemm_bf<1, 256><<<dim3(17, M_ / 256), 512, 0, stream>>>(
        xinh, W2, 2048, nullptr, nullptr, nullptr, A_proj_b, amod, Bin, Cin);

    // chunked scan
    scan_phase1<<<dim3(DIN_ / 256, NCHUNK, B_), 256, 0, stream>>>(amod, xinh, Bin, A_base, Pw, Sw);
    scan_phase2<<<(B_ * DIN_ * NS_) / 256, 256, 0, stream>>>(Pw, Sw, H0w);
    scan_phase3<<<dim3(DIN_ / 256, NCHUNK, B_), 256, 0, stream>>>(
        amod, xinh, Bin, Cin, A_base, H0w, Dp, szh, yh);

    // out = residual + y @ out_proj  (N=1024, K=2048), 64x128 tiles -> 512 blocks
    gemm_bf<2, 64><<<dim3(1024 / 128, M_ / 64), 256, 0, stream>>>(
        yh, outT, 2048, out, nullptr, nullptr, x, nullptr, nullptr, nullptr);
}